// Round 1
// baseline (2562.262 us; speedup 1.0000x reference)
//
#include <hip/hip_runtime.h>
#include <cstdint>
#include <cstddef>

#define NB 8
#define NN 512
#define ND 256
#define NH 8
#define NM 8
#define NK 16
#define NR 8
#define NDH 32
// derived
#define BN (NB*NN)           // 4096 rows
#define BH (NB*NH)           // 64
#define BHN (BH*NN)          // 32768
#define BHM (BH*NM)          // 512
#define SLAB (NN*NK)         // 8192  (per-(b,h,m) Pi/C/K slab)

// ---------------- MLP ----------------
__global__ void k_mlp1(const float* __restrict__ xd, const float* __restrict__ xn,
                       const float* __restrict__ W1, const float* __restrict__ b1,
                       float* __restrict__ hid) {
  __shared__ float As[16][17], Bs[16][17];
  int tx = threadIdx.x, ty = threadIdx.y;
  int j = blockIdx.x*16 + tx;          // out col [0,256)
  int r = blockIdx.y*16 + ty;          // row [0,4096)
  float acc = 0.f;
  for (int c0 = 0; c0 < 2*ND; c0 += 16) {
    int c = c0 + tx;
    As[ty][tx] = (c < ND) ? xd[r*ND + c] : xn[r*ND + (c-ND)];
    Bs[ty][tx] = W1[(c0+ty)*ND + j];
    __syncthreads();
    #pragma unroll
    for (int kk = 0; kk < 16; kk++) acc += As[ty][kk]*Bs[kk][tx];
    __syncthreads();
  }
  hid[r*ND + j] = fmaxf(acc + b1[j], 0.f);
}

__global__ void k_mlp2(const float* __restrict__ hid,
                       const float* __restrict__ W2, const float* __restrict__ b2,
                       float* __restrict__ z) {
  __shared__ float As[16][17], Bs[16][17];
  int tx = threadIdx.x, ty = threadIdx.y;
  int j = blockIdx.x*16 + tx;
  int r = blockIdx.y*16 + ty;
  float acc = 0.f;
  for (int c0 = 0; c0 < ND; c0 += 16) {
    As[ty][tx] = hid[r*ND + c0 + tx];
    Bs[ty][tx] = W2[(c0+ty)*ND + j];
    __syncthreads();
    #pragma unroll
    for (int kk = 0; kk < 16; kk++) acc += As[ty][kk]*Bs[kk][tx];
    __syncthreads();
  }
  z[r*ND + j] = acc + b2[j];
}

// ---------------- zh normalize ----------------
__global__ void k_zhnorm(const float* __restrict__ z, float* __restrict__ zh) {
  int idx = blockIdx.x*256 + threadIdx.x;    // B*H*N*32 = 1,048,576
  int d = idx & 31;
  int n = (idx >> 5) & (NN-1);
  int h = (idx >> 14) & (NH-1);
  int b = idx >> 17;
  float v = z[(b*NN + n)*ND + h*NDH + d];
  float ss = v*v;
  #pragma unroll
  for (int m = 1; m < 32; m <<= 1) ss += __shfl_xor(ss, m);
  zh[idx] = v / fmaxf(sqrtf(ss), 1e-8f);
}

// ---------------- affinity + softmax -> P ----------------
__global__ void k_affinity(const float* __restrict__ zh, float* __restrict__ P) {
  int bhn = blockIdx.x;                 // 32768
  int n = bhn & (NN-1);
  int bh = bhn >> 9;
  const float* base = zh + (size_t)bh*NN*NDH;
  __shared__ float qrow[32];
  __shared__ float red[256];
  int t = threadIdx.x;
  if (t < 32) qrow[t] = base[n*32 + t];
  __syncthreads();
  float lg[2];
  #pragma unroll
  for (int i = 0; i < 2; i++) {
    int s = t + i*256;
    const float* krow = base + s*32;
    float acc = 0.f;
    #pragma unroll
    for (int d = 0; d < 32; d++) acc += qrow[d]*krow[d];
    lg[i] = (s == n) ? -1e9f : acc*0.0625f;   // SCALE/TAU_AFF = 1/16
  }
  red[t] = fmaxf(lg[0], lg[1]); __syncthreads();
  for (int s = 128; s > 0; s >>= 1) { if (t < s) red[t] = fmaxf(red[t], red[t+s]); __syncthreads(); }
  float mx = red[0]; __syncthreads();
  float e0 = expf(lg[0]-mx), e1 = expf(lg[1]-mx);
  red[t] = e0 + e1; __syncthreads();
  for (int s = 128; s > 0; s >>= 1) { if (t < s) red[t] += red[t+s]; __syncthreads(); }
  float inv = 1.f / red[0];
  float* prow = P + (size_t)bhn*NN;
  prow[t] = e0*inv; prow[t+256] = e1*inv;
}

// ---------------- symmetrize, row-normalize -> DP ----------------
__global__ void k_dp(const float* __restrict__ P, float* __restrict__ DPo) {
  int bhn = blockIdx.x;
  int n = bhn & (NN-1);
  int bh = bhn >> 9;
  const float* Pb = P + (size_t)bh*NN*NN;
  __shared__ float red[256];
  int t = threadIdx.x;
  float sv[2];
  #pragma unroll
  for (int i = 0; i < 2; i++) {
    int s = t + i*256;
    float a = Pb[(size_t)n*NN + s];
    float bt = Pb[(size_t)s*NN + n];
    sv[i] = fmaxf(0.5f*(a+bt), 1e-8f);
  }
  red[t] = sv[0] + sv[1]; __syncthreads();
  for (int s = 128; s > 0; s >>= 1) { if (t < s) red[t] += red[t+s]; __syncthreads(); }
  float inv = 1.f / fmaxf(red[0], 1e-8f);
  float* drow = DPo + (size_t)bhn*NN;
  drow[t]     = fmaxf(1.f - sv[0]*inv, 0.f);
  drow[t+256] = fmaxf(1.f - sv[1]*inv, 0.f);
}

// ---------------- slot graphs: G, g_reg, DG ----------------
__global__ void k_slots(const float* __restrict__ Up, float* __restrict__ G,
                        float* __restrict__ DG, float* __restrict__ greg,
                        float* __restrict__ usage) {
  __shared__ float U[NM*NK*NR];      // 1024
  __shared__ float Gs[NM*NK*NK];     // 2048
  __shared__ float rs[NM*NK];        // 128
  __shared__ float vn[NM];
  __shared__ float gram[NM*NM];
  int t = threadIdx.x;
  for (int i = t; i < NM*NK*NR; i += 256) {
    float x = Up[i];
    U[i] = fmaxf(x, 0.f) + log1pf(expf(-fabsf(x)));   // stable softplus
  }
  __syncthreads();
  for (int i = t; i < NM*NK*NK; i += 256) {
    int m = i >> 8, k = (i >> 4) & 15, j = i & 15;
    float acc = 0.f;
    #pragma unroll
    for (int r = 0; r < NR; r++) acc += U[(m*NK+k)*NR + r]*U[(m*NK+j)*NR + r];
    Gs[i] = acc;
  }
  __syncthreads();
  for (int i = t; i < NM*NK; i += 256) {
    float s = 0.f;
    #pragma unroll
    for (int j = 0; j < NK; j++) s += Gs[i*NK + j];
    rs[i] = fmaxf(s, 1e-8f);
  }
  __syncthreads();
  for (int i = t; i < NM*NK*NK; i += 256) { Gs[i] /= rs[i >> 4]; G[i] = Gs[i]; }
  __syncthreads();
  for (int i = t; i < NM; i += 256) {
    float s = 0.f;
    for (int j = 0; j < NK*NK; j++) { float g = Gs[i*NK*NK + j]; s += g*g; }
    vn[i] = fmaxf(sqrtf(s), 1e-8f);
  }
  __syncthreads();
  for (int i = t; i < NM*NM; i += 256) {
    int a = i >> 3, b = i & 7;
    float s = 0.f;
    for (int j = 0; j < NK*NK; j++) s += Gs[a*NK*NK + j]*Gs[b*NK*NK + j];
    gram[i] = s / (vn[a]*vn[b]);
  }
  __syncthreads();
  if (t == 0) {
    float s = 0.f;
    for (int i = 0; i < NM*NM; i++) if ((i >> 3) != (i & 7)) s += gram[i];
    greg[0] = 0.1f * s / (float)(NM*(NM-1));
    for (int m = 0; m < NM; m++) usage[m] = 0.f;
  }
  for (int i = t; i < NM*NK*NK; i += 256) {
    int m = i >> 8, k = (i >> 4) & 15, j = i & 15;
    float dk = fmaxf(Gs[m*NK*NK + k*NK + k], 1e-8f);
    float dj = fmaxf(Gs[m*NK*NK + j*NK + j], 1e-8f);
    float den = fmaxf(sqrtf(dk*dj), 1e-8f);
    float c = fminf(fmaxf(Gs[i]/den, -1.f), 1.f);
    float d = fmaxf(1.f - c, 0.f);
    if (k == j) d = 0.f;
    DG[i] = d;
  }
}

// ---------------- Pi init ----------------
__global__ void k_fillpi(float* __restrict__ Pi) {
  int idx = blockIdx.x*256 + threadIdx.x;   // 4,194,304
  Pi[idx] = 1.f / (float)(NN*NK);
}

// ---------------- marginals ----------------
__global__ void k_mass(const float* __restrict__ Pi, float* __restrict__ massj,
                       float* __restrict__ massl) {
  int bhm = blockIdx.x;   // 512
  const float* Pb = Pi + (size_t)bhm*SLAB;
  __shared__ float red[256][17];
  int t = threadIdx.x;
  float accl[NK];
  #pragma unroll
  for (int k = 0; k < NK; k++) accl[k] = 0.f;
  #pragma unroll
  for (int i = 0; i < 2; i++) {
    int n = t + i*256;
    float s = 0.f;
    #pragma unroll
    for (int k = 0; k < NK; k++) { float p = Pb[n*NK + k]; s += p; accl[k] += p; }
    massj[bhm*NN + n] = s;
  }
  #pragma unroll
  for (int k = 0; k < NK; k++) red[t][k] = accl[k];
  __syncthreads();
  for (int s = 128; s > 0; s >>= 1) {
    if (t < s) { for (int k = 0; k < NK; k++) red[t][k] += red[t+s][k]; }
    __syncthreads();
  }
  if (t < NK) massl[bhm*NK + t] = red[0][t];
}

// ---------------- term1[b,h,m,i] = sum_j DP^2[i,j] * massj[m,j] ----------------
__global__ void k_term1(const float* __restrict__ DPm, const float* __restrict__ massj,
                        float* __restrict__ term1) {
  int bhn = blockIdx.x;   // 32768
  int n = bhn & (NN-1);
  int bh = bhn >> 9;
  __shared__ float mj[NM*NN];     // 16KB
  __shared__ float red[256][9];
  int t = threadIdx.x;
  for (int i = t; i < NM*NN; i += 256) mj[i] = massj[bh*NM*NN + i];
  __syncthreads();
  float acc[NM];
  #pragma unroll
  for (int m = 0; m < NM; m++) acc[m] = 0.f;
  const float* dpr = DPm + (size_t)bhn*NN;
  for (int j = t; j < NN; j += 256) {
    float dp = dpr[j]; float d2 = dp*dp;
    #pragma unroll
    for (int m = 0; m < NM; m++) acc[m] += d2*mj[m*NN + j];
  }
  #pragma unroll
  for (int m = 0; m < NM; m++) red[t][m] = acc[m];
  __syncthreads();
  for (int s = 128; s > 0; s >>= 1) {
    if (t < s) { for (int m = 0; m < NM; m++) red[t][m] += red[t+s][m]; }
    __syncthreads();
  }
  if (t < NM) term1[(bh*NM + t)*NN + n] = red[0][t];
}

// ---------------- term2[b,h,m,k] = sum_l DG^2[m,k,l]*massl[m,l] ----------------
__global__ void k_term2(const float* __restrict__ DG, const float* __restrict__ massl,
                        float* __restrict__ term2) {
  int idx = blockIdx.x*256 + threadIdx.x;   // 65536... grid=256 -> 65536? grid 256*256=65536? no: 256 blocks
  // idx in [0, BHM*NK) = 8192*... BHM*NK = 8192
  if (idx >= BHM*NK) return;
  int k = idx & 15, bhm = idx >> 4;
  int m = bhm & 7;
  float s = 0.f;
  #pragma unroll
  for (int l = 0; l < NK; l++) { float d = DG[(m*NK + k)*NK + l]; s += d*d*massl[bhm*NK + l]; }
  term2[idx] = s;
}

// ---------------- C and Kmat ----------------
__global__ void k_cost(const float* __restrict__ DPm, const float* __restrict__ Pi,
                       const float* __restrict__ DG, const float* __restrict__ term1,
                       const float* __restrict__ term2, float* __restrict__ C,
                       float* __restrict__ Km) {
  int blk = blockIdx.x;          // 8192 = BHM * 16 tiles
  int itile = blk & 15;
  int bhm = blk >> 4;
  int m = bhm & 7;
  int bh = bhm >> 3;
  __shared__ float dps[32][33];
  __shared__ float pis[32][17];
  __shared__ float W[32][17];
  int t = threadIdx.x;           // 512 threads
  int il = t >> 4;               // 0..31
  int ll = t & 15;               // 0..15
  float w = 0.f;
  const float* DPb = DPm + (size_t)bh*NN*NN + (size_t)(itile*32)*NN;
  const float* Pib = Pi + (size_t)bhm*SLAB;
  for (int j0 = 0; j0 < NN; j0 += 32) {
    int f0 = t, f1 = t + 512;
    dps[f0 >> 5][f0 & 31] = DPb[(f0 >> 5)*NN + j0 + (f0 & 31)];
    dps[f1 >> 5][f1 & 31] = DPb[(f1 >> 5)*NN + j0 + (f1 & 31)];
    pis[t >> 4][t & 15] = Pib[j0*NK + t];
    __syncthreads();
    #pragma unroll
    for (int jj = 0; jj < 32; jj++) w += dps[il][jj]*pis[jj][ll];
    __syncthreads();
  }
  W[il][ll] = w;
  __syncthreads();
  int i = itile*32 + il;
  float t1 = term1[bhm*NN + i];
  float t2 = term2[bhm*NK + ll];
  float cr = 0.f;
  #pragma unroll
  for (int l = 0; l < NK; l++) cr += W[il][l]*DG[(m*NK + ll)*NK + l];
  float c = fmaxf(t1 + t2 - 2.f*cr, 0.f);
  size_t o = (size_t)bhm*SLAB + (size_t)i*NK + ll;
  C[o] = c;
  Km[o] = fmaxf(expf(-20.f*c), 1e-12f);   // exp(-C/GW_EPS), GW_EPS=0.05
}

// ---------------- sinkhorn (10 iters fused) -> Pi ----------------
__global__ void k_sinkhorn(const float* __restrict__ Km, float* __restrict__ Pi) {
  int bhm = blockIdx.x;   // 512
  const float* Kb = Km + (size_t)bhm*SLAB;
  __shared__ float KT[NK][NN+1];      // transposed, 32.8KB
  __shared__ float u[NN];
  __shared__ float v[NK];
  __shared__ float red[256][17];
  int t = threadIdx.x;
  for (int i = t; i < SLAB; i += 256) KT[i & 15][i >> 4] = Kb[i];
  if (t < NK) v[t] = 1.f/16.f;
  __syncthreads();
  for (int it = 0; it < 10; ++it) {
    #pragma unroll
    for (int i = 0; i < 2; i++) {
      int n = t + i*256;
      float s = 0.f;
      #pragma unroll
      for (int k = 0; k < NK; k++) s += KT[k][n]*v[k];
      u[n] = (1.f/512.f)/(s + 1e-6f);
    }
    __syncthreads();
    float accl[NK];
    #pragma unroll
    for (int k = 0; k < NK; k++) accl[k] = 0.f;
    #pragma unroll
    for (int i = 0; i < 2; i++) {
      int n = t + i*256; float un = u[n];
      #pragma unroll
      for (int k = 0; k < NK; k++) accl[k] += KT[k][n]*un;
    }
    #pragma unroll
    for (int k = 0; k < NK; k++) red[t][k] = accl[k];
    __syncthreads();
    for (int s = 128; s > 0; s >>= 1) {
      if (t < s) { for (int k = 0; k < NK; k++) red[t][k] += red[t+s][k]; }
      __syncthreads();
    }
    if (t < NK) v[t] = (1.f/16.f)/(red[0][t] + 1e-6f);
    __syncthreads();
  }
  float* Pib = Pi + (size_t)bhm*SLAB;
  for (int i = t; i < SLAB; i += 256) {
    int n = i >> 4, k = i & 15;
    Pib[i] = u[n]*KT[k][n]*v[k];
  }
}

// ---------------- gw_val ----------------
__global__ void k_gwval(const float* __restrict__ C, const float* __restrict__ Pi,
                        float* __restrict__ gw) {
  int bhm = blockIdx.x; int t = threadIdx.x;
  __shared__ float red[256];
  const float* Cb = C + (size_t)bhm*SLAB;
  const float* Pb = Pi + (size_t)bhm*SLAB;
  float s = 0.f;
  for (int i = t; i < SLAB; i += 256) s += Cb[i]*Pb[i];
  red[t] = s; __syncthreads();
  for (int q = 128; q > 0; q >>= 1) { if (t < q) red[t] += red[t+q]; __syncthreads(); }
  if (t == 0) gw[bhm] = red[0];
}

// ---------------- alpha ----------------
__global__ void k_alpha(const float* __restrict__ gw, float* __restrict__ alpha) {
  int t = threadIdx.x;   // 512 = BHM
  float g = gw[t];
  float sc = expf(-(g*g));          // GW_SIGMA = 1
  float s = sc;
  s += __shfl_xor(s, 1); s += __shfl_xor(s, 2); s += __shfl_xor(s, 4);
  alpha[t] = sc / fmaxf(s, 1e-8f);
}

// ---------------- Qmix (raw, pre-normalize) ----------------
__global__ void k_qmix(const float* __restrict__ Pi, const float* __restrict__ G,
                       const float* __restrict__ alpha, float* __restrict__ Qraw) {
  int blk = blockIdx.x;             // 64 * 16 * 16 = 16384
  int st = blk & 15;
  int nt = (blk >> 4) & 15;
  int bh = blk >> 8;
  __shared__ float Pn[32][17], Ps[32][17], Gs[16][16], Tn[32][17];
  int t = threadIdx.x;              // 256
  int ii = t >> 5;                  // 0..7
  int ss = t & 31;                  // 0..31
  float acc[4] = {0.f, 0.f, 0.f, 0.f};
  for (int m = 0; m < NM; m++) {
    const float* Pib = Pi + ((size_t)(bh*NM + m))*SLAB;
    #pragma unroll
    for (int q = 0; q < 2; q++) {
      int idx = t + q*256;
      Pn[idx >> 4][idx & 15] = Pib[nt*512 + idx];
      Ps[idx >> 4][idx & 15] = Pib[st*512 + idx];
    }
    Gs[t >> 4][t & 15] = G[m*NK*NK + t];
    __syncthreads();
    #pragma unroll
    for (int q = 0; q < 2; q++) {
      int idx = t + q*256;
      int i = idx >> 4, l = idx & 15;
      float s2 = 0.f;
      #pragma unroll
      for (int k = 0; k < NK; k++) s2 += Pn[i][k]*Gs[k][l];
      Tn[i][l] = s2;
    }
    __syncthreads();
    float al = alpha[bh*NM + m];
    #pragma unroll
    for (int q = 0; q < 4; q++) {
      int i = ii + q*8;
      float s2 = 0.f;
      #pragma unroll
      for (int l = 0; l < NK; l++) s2 += Tn[i][l]*Ps[ss][l];
      acc[q] += al*s2;
    }
    __syncthreads();
  }
  float* Qb = Qraw + (size_t)bh*NN*NN;
  #pragma unroll
  for (int q = 0; q < 4; q++) {
    int i = nt*32 + ii + q*8;
    int s = st*32 + ss;
    Qb[(size_t)i*NN + s] = acc[q];
  }
}

// ---------------- normalize Q + bias_log ----------------
__global__ void k_qnorm(float* __restrict__ out) {
  int bhn = blockIdx.x;
  int t = threadIdx.x;
  float* Qrow = out + (size_t)16777216 + (size_t)bhn*NN;
  float* Brow = out + (size_t)bhn*NN;
  __shared__ float red[256];
  float q0 = fmaxf(Qrow[t], 1e-8f), q1 = fmaxf(Qrow[t+256], 1e-8f);
  red[t] = q0 + q1; __syncthreads();
  for (int s = 128; s > 0; s >>= 1) { if (t < s) red[t] += red[t+s]; __syncthreads(); }
  float inv = 1.f / red[0];
  float a = q0*inv, b = q1*inv;
  Qrow[t] = a; Qrow[t+256] = b;
  Brow[t] = logf(a); Brow[t+256] = logf(b);
}

// ---------------- slot usage ----------------
__global__ void k_usage(const float* __restrict__ z, const float* __restrict__ Wp,
                        const float* __restrict__ bp, float* __restrict__ usage) {
  int r = blockIdx.x;   // 4096
  int t = threadIdx.x;  // 256
  __shared__ float red[256][9];
  float zv = z[(size_t)r*ND + t];
  #pragma unroll
  for (int m = 0; m < NM; m++) red[t][m] = zv*Wp[t*NM + m];
  __syncthreads();
  for (int s = 128; s > 0; s >>= 1) {
    if (t < s) { for (int m = 0; m < NM; m++) red[t][m] += red[t+s][m]; }
    __syncthreads();
  }
  if (t == 0) {
    float lg[NM]; float mx = -1e30f;
    #pragma unroll
    for (int m = 0; m < NM; m++) { lg[m] = red[0][m] + bp[m]; mx = fmaxf(mx, lg[m]); }
    float s = 0.f;
    #pragma unroll
    for (int m = 0; m < NM; m++) { lg[m] = expf(lg[m]-mx); s += lg[m]; }
    #pragma unroll
    for (int m = 0; m < NM; m++) atomicAdd(&usage[m], lg[m]/s);
  }
}

// ---------------- final scalar ----------------
__global__ void k_final(const float* __restrict__ greg, const float* __restrict__ usage,
                        float* __restrict__ out) {
  if (threadIdx.x == 0) {
    float kl = 0.f;
    for (int m = 0; m < NM; m++) {
      float u = usage[m] / (float)BN;
      kl += u*logf(fmaxf(u, 1e-8f)*(float)NM);
    }
    out[33554432] = greg[0] + 0.01f*kl;
  }
}

extern "C" void kernel_launch(void* const* d_in, const int* in_sizes, int n_in,
                              void* d_out, int out_size, void* d_ws, size_t ws_size,
                              hipStream_t stream) {
  const float* xd = (const float*)d_in[0];
  const float* xn = (const float*)d_in[1];
  const float* W1 = (const float*)d_in[2];
  const float* b1 = (const float*)d_in[3];
  const float* W2 = (const float*)d_in[4];
  const float* b2 = (const float*)d_in[5];
  const float* Wp = (const float*)d_in[6];
  const float* bp = (const float*)d_in[7];
  const float* Up = (const float*)d_in[8];
  float* out = (float*)d_out;
  float* ws  = (float*)d_ws;

  float* z     = ws + 0;
  float* hid   = ws + 1048576;
  float* zh    = ws + 2097152;
  float* Pi    = ws + 3145728;    // 4,194,304
  float* C     = ws + 7340032;    // 4,194,304
  float* Km    = ws + 11534336;   // 4,194,304
  float* massj = ws + 15728640;   // 262,144
  float* term1 = ws + 15990784;   // 262,144
  float* massl = ws + 16252928;   // 8,192
  float* term2 = ws + 16261120;   // 8,192
  float* gw    = ws + 16269312;   // 512
  float* alpha = ws + 16269824;   // 512
  float* G     = ws + 16270336;   // 2,048
  float* DG    = ws + 16272384;   // 2,048
  float* greg  = ws + 16274432;   // 1
  float* usage = ws + 16274433;   // 8

  // d_out doubles as scratch: P in bias_log region, DP in Q region.
  float* P  = out;
  float* DP = out + 16777216;

  k_mlp1<<<dim3(16, 256), dim3(16, 16), 0, stream>>>(xd, xn, W1, b1, hid);
  k_mlp2<<<dim3(16, 256), dim3(16, 16), 0, stream>>>(hid, W2, b2, z);
  k_zhnorm<<<4096, 256, 0, stream>>>(z, zh);
  k_affinity<<<BHN, 256, 0, stream>>>(zh, P);
  k_dp<<<BHN, 256, 0, stream>>>(P, DP);
  k_slots<<<1, 256, 0, stream>>>(Up, G, DG, greg, usage);
  k_fillpi<<<16384, 256, 0, stream>>>(Pi);
  for (int it = 0; it < 3; ++it) {
    k_mass<<<BHM, 256, 0, stream>>>(Pi, massj, massl);
    k_term1<<<BHN, 256, 0, stream>>>(DP, massj, term1);
    k_term2<<<32, 256, 0, stream>>>(DG, massl, term2);
    k_cost<<<BHM*16, 512, 0, stream>>>(DP, Pi, DG, term1, term2, C, Km);
    k_sinkhorn<<<BHM, 256, 0, stream>>>(Km, Pi);
  }
  k_gwval<<<BHM, 256, 0, stream>>>(C, Pi, gw);
  k_alpha<<<1, 512, 0, stream>>>(gw, alpha);
  k_qmix<<<16384, 256, 0, stream>>>(Pi, G, alpha, out + 16777216);
  k_qnorm<<<BHN, 256, 0, stream>>>(out);
  k_usage<<<4096, 256, 0, stream>>>(z, Wp, bp, usage);
  k_final<<<1, 64, 0, stream>>>(greg, usage, out);
}

// Round 2
// 1136.109 us; speedup vs baseline: 2.2553x; 2.2553x over previous
//
#include <hip/hip_runtime.h>
#include <cstdint>
#include <cstddef>

#define NB 8
#define NN 512
#define ND 256
#define NH 8
#define NM 8
#define NK 16
#define NR 8
#define NDH 32
#define BN (NB*NN)           // 4096 rows
#define BH (NB*NH)           // 64
#define BHN (BH*NN)          // 32768
#define BHM (BH*NM)          // 512
#define SLAB (NN*NK)         // 8192

// ---------------- MLP: 64x64 tile, 4x4 per thread ----------------
__global__ __launch_bounds__(256) void k_mlp1(const float* __restrict__ xd, const float* __restrict__ xn,
                       const float* __restrict__ W1, const float* __restrict__ b1,
                       float* __restrict__ hid) {
  __shared__ float As[16][68];   // [k][i]
  __shared__ float Bs[16][68];   // [k][j]
  int t = threadIdx.x;
  int col0 = blockIdx.x * 64;
  int row0 = blockIdx.y * 64;
  int ar = t >> 2, ak = (t & 3) * 4;
  int bk = t >> 4, bc = (t & 15) * 4;
  int ty = t >> 4, tx = t & 15;
  float acc[4][4] = {};
  for (int k0 = 0; k0 < 2*ND; k0 += 16) {
    int gk = k0 + ak;
    const float* src = (gk < ND) ? (xd + (size_t)(row0+ar)*ND + gk)
                                 : (xn + (size_t)(row0+ar)*ND + (gk-ND));
    float4 av = *(const float4*)src;
    As[ak+0][ar] = av.x; As[ak+1][ar] = av.y; As[ak+2][ar] = av.z; As[ak+3][ar] = av.w;
    float4 bv = *(const float4*)(W1 + (size_t)(k0+bk)*ND + col0 + bc);
    *(float4*)&Bs[bk][bc] = bv;
    __syncthreads();
    #pragma unroll
    for (int kk = 0; kk < 16; kk++) {
      float4 a = *(const float4*)&As[kk][ty*4];
      float4 b = *(const float4*)&Bs[kk][tx*4];
      acc[0][0] += a.x*b.x; acc[0][1] += a.x*b.y; acc[0][2] += a.x*b.z; acc[0][3] += a.x*b.w;
      acc[1][0] += a.y*b.x; acc[1][1] += a.y*b.y; acc[1][2] += a.y*b.z; acc[1][3] += a.y*b.w;
      acc[2][0] += a.z*b.x; acc[2][1] += a.z*b.y; acc[2][2] += a.z*b.z; acc[2][3] += a.z*b.w;
      acc[3][0] += a.w*b.x; acc[3][1] += a.w*b.y; acc[3][2] += a.w*b.z; acc[3][3] += a.w*b.w;
    }
    __syncthreads();
  }
  float4 bb = *(const float4*)(b1 + col0 + tx*4);
  #pragma unroll
  for (int a = 0; a < 4; a++) {
    float4 o;
    o.x = fmaxf(acc[a][0] + bb.x, 0.f);
    o.y = fmaxf(acc[a][1] + bb.y, 0.f);
    o.z = fmaxf(acc[a][2] + bb.z, 0.f);
    o.w = fmaxf(acc[a][3] + bb.w, 0.f);
    *(float4*)(hid + (size_t)(row0+ty*4+a)*ND + col0 + tx*4) = o;
  }
}

__global__ __launch_bounds__(256) void k_mlp2(const float* __restrict__ hidp,
                       const float* __restrict__ W2, const float* __restrict__ b2,
                       float* __restrict__ z) {
  __shared__ float As[16][68];
  __shared__ float Bs[16][68];
  int t = threadIdx.x;
  int col0 = blockIdx.x * 64;
  int row0 = blockIdx.y * 64;
  int ar = t >> 2, ak = (t & 3) * 4;
  int bk = t >> 4, bc = (t & 15) * 4;
  int ty = t >> 4, tx = t & 15;
  float acc[4][4] = {};
  for (int k0 = 0; k0 < ND; k0 += 16) {
    float4 av = *(const float4*)(hidp + (size_t)(row0+ar)*ND + k0 + ak);
    As[ak+0][ar] = av.x; As[ak+1][ar] = av.y; As[ak+2][ar] = av.z; As[ak+3][ar] = av.w;
    float4 bv = *(const float4*)(W2 + (size_t)(k0+bk)*ND + col0 + bc);
    *(float4*)&Bs[bk][bc] = bv;
    __syncthreads();
    #pragma unroll
    for (int kk = 0; kk < 16; kk++) {
      float4 a = *(const float4*)&As[kk][ty*4];
      float4 b = *(const float4*)&Bs[kk][tx*4];
      acc[0][0] += a.x*b.x; acc[0][1] += a.x*b.y; acc[0][2] += a.x*b.z; acc[0][3] += a.x*b.w;
      acc[1][0] += a.y*b.x; acc[1][1] += a.y*b.y; acc[1][2] += a.y*b.z; acc[1][3] += a.y*b.w;
      acc[2][0] += a.z*b.x; acc[2][1] += a.z*b.y; acc[2][2] += a.z*b.z; acc[2][3] += a.z*b.w;
      acc[3][0] += a.w*b.x; acc[3][1] += a.w*b.y; acc[3][2] += a.w*b.z; acc[3][3] += a.w*b.w;
    }
    __syncthreads();
  }
  float4 bb = *(const float4*)(b2 + col0 + tx*4);
  #pragma unroll
  for (int a = 0; a < 4; a++) {
    float4 o;
    o.x = acc[a][0] + bb.x; o.y = acc[a][1] + bb.y;
    o.z = acc[a][2] + bb.z; o.w = acc[a][3] + bb.w;
    *(float4*)(z + (size_t)(row0+ty*4+a)*ND + col0 + tx*4) = o;
  }
}

// ---------------- zh normalize ----------------
__global__ void k_zhnorm(const float* __restrict__ z, float* __restrict__ zh) {
  int idx = blockIdx.x*256 + threadIdx.x;
  int d = idx & 31;
  int n = (idx >> 5) & (NN-1);
  int h = (idx >> 14) & (NH-1);
  int b = idx >> 17;
  float v = z[(size_t)(b*NN + n)*ND + h*NDH + d];
  float ss = v*v;
  #pragma unroll
  for (int m = 1; m < 32; m <<= 1) ss += __shfl_xor(ss, m);
  zh[idx] = v / fmaxf(sqrtf(ss), 1e-8f);
}

// ---------------- affinity + softmax -> P (32-row panel, regs) ----------------
__global__ __launch_bounds__(256) void k_affinity(const float* __restrict__ zh, float* __restrict__ P) {
  int blk = blockIdx.x;               // 64 bh * 16 rowtiles
  int rt = blk & 15, bh = blk >> 4;
  int r0 = rt*32;
  const float* base = zh + (size_t)bh*NN*NDH;
  __shared__ float qs[32][33];
  __shared__ float ks[32][36];        // [d][s]
  int t = threadIdx.x;
  int sr = t >> 3, dq = (t & 7)*4;
  {
    float4 v = *(const float4*)(base + (size_t)(r0+sr)*NDH + dq);
    qs[sr][dq] = v.x; qs[sr][dq+1] = v.y; qs[sr][dq+2] = v.z; qs[sr][dq+3] = v.w;
  }
  int cr = t >> 3;        // row 0..31 (8 consecutive lanes per row)
  int cq = t & 7;         // col group
  float acc[16][4];
  #pragma unroll
  for (int ti = 0; ti < 16; ti++) { acc[ti][0]=0; acc[ti][1]=0; acc[ti][2]=0; acc[ti][3]=0; }
  for (int ti = 0; ti < 16; ti++) {
    int s0 = ti*32;
    __syncthreads();
    {
      float4 v = *(const float4*)(base + (size_t)(s0+sr)*NDH + dq);
      ks[dq+0][sr] = v.x; ks[dq+1][sr] = v.y; ks[dq+2][sr] = v.z; ks[dq+3][sr] = v.w;
    }
    __syncthreads();
    #pragma unroll
    for (int d = 0; d < 32; d++) {
      float qv = qs[cr][d];
      float4 kv = *(const float4*)&ks[d][cq*4];
      acc[ti][0] += qv*kv.x; acc[ti][1] += qv*kv.y;
      acc[ti][2] += qv*kv.z; acc[ti][3] += qv*kv.w;
    }
  }
  // scale + diag mask + running max
  int gr = r0 + cr;
  float mx = -1e30f;
  #pragma unroll
  for (int ti = 0; ti < 16; ti++) {
    #pragma unroll
    for (int j = 0; j < 4; j++) {
      int s = ti*32 + cq*4 + j;
      float v = (s == gr) ? -1e9f : acc[ti][j]*0.0625f;
      acc[ti][j] = v;
      mx = fmaxf(mx, v);
    }
  }
  mx = fmaxf(mx, __shfl_xor(mx, 1));
  mx = fmaxf(mx, __shfl_xor(mx, 2));
  mx = fmaxf(mx, __shfl_xor(mx, 4));
  float sum = 0.f;
  #pragma unroll
  for (int ti = 0; ti < 16; ti++) {
    #pragma unroll
    for (int j = 0; j < 4; j++) { float e = expf(acc[ti][j]-mx); acc[ti][j] = e; sum += e; }
  }
  sum += __shfl_xor(sum,1); sum += __shfl_xor(sum,2); sum += __shfl_xor(sum,4);
  float inv = 1.f/sum;
  float* prow = P + ((size_t)(bh*NN) + gr)*NN;
  #pragma unroll
  for (int ti = 0; ti < 16; ti++) {
    float4 o; o.x = acc[ti][0]*inv; o.y = acc[ti][1]*inv; o.z = acc[ti][2]*inv; o.w = acc[ti][3]*inv;
    *(float4*)(prow + ti*32 + cq*4) = o;
  }
}

// ---------------- DP: symmetrize + row-normalize (32-row panel, regs) ----------------
__global__ __launch_bounds__(256) void k_dp(const float* __restrict__ P, float* __restrict__ DPo) {
  int blk = blockIdx.x;               // 64*16
  int rt = blk & 15, bh = blk >> 4;
  int r0 = rt*32;
  const float* Pb = P + (size_t)bh*NN*NN;
  __shared__ float Bs[32][33];
  int t = threadIdx.x;
  int r = t >> 3, q4 = (t & 7)*4;
  float pn[16][4];
  float rowacc = 0.f;
  for (int ti = 0; ti < 16; ti++) {
    int s0 = ti*32;
    __syncthreads();
    {
      float4 v = *(const float4*)(Pb + (size_t)(s0+r)*NN + r0 + q4);
      Bs[r][q4] = v.x; Bs[r][q4+1] = v.y; Bs[r][q4+2] = v.z; Bs[r][q4+3] = v.w;
    }
    float4 a = *(const float4*)(Pb + (size_t)(r0+r)*NN + s0 + q4);
    __syncthreads();
    float p0 = fmaxf(0.5f*(a.x + Bs[q4+0][r]), 1e-8f);
    float p1 = fmaxf(0.5f*(a.y + Bs[q4+1][r]), 1e-8f);
    float p2 = fmaxf(0.5f*(a.z + Bs[q4+2][r]), 1e-8f);
    float p3 = fmaxf(0.5f*(a.w + Bs[q4+3][r]), 1e-8f);
    pn[ti][0]=p0; pn[ti][1]=p1; pn[ti][2]=p2; pn[ti][3]=p3;
    rowacc += p0+p1+p2+p3;
  }
  rowacc += __shfl_xor(rowacc,1); rowacc += __shfl_xor(rowacc,2); rowacc += __shfl_xor(rowacc,4);
  float inv = 1.f / fmaxf(rowacc, 1e-8f);
  float* drow = DPo + ((size_t)(bh*NN) + r0 + r)*NN;
  #pragma unroll
  for (int ti = 0; ti < 16; ti++) {
    float4 o;
    o.x = fmaxf(1.f - pn[ti][0]*inv, 0.f);
    o.y = fmaxf(1.f - pn[ti][1]*inv, 0.f);
    o.z = fmaxf(1.f - pn[ti][2]*inv, 0.f);
    o.w = fmaxf(1.f - pn[ti][3]*inv, 0.f);
    *(float4*)(drow + ti*32 + q4) = o;
  }
}

// ---------------- slot graphs: G, g_reg, DG ----------------
__global__ void k_slots(const float* __restrict__ Up, float* __restrict__ G,
                        float* __restrict__ DG, float* __restrict__ greg) {
  __shared__ float U[NM*NK*NR];
  __shared__ float Gs[NM*NK*NK];
  __shared__ float rs[NM*NK];
  __shared__ float vn[NM];
  __shared__ float gram[NM*NM];
  int t = threadIdx.x;
  for (int i = t; i < NM*NK*NR; i += 256) {
    float x = Up[i];
    U[i] = fmaxf(x, 0.f) + log1pf(expf(-fabsf(x)));
  }
  __syncthreads();
  for (int i = t; i < NM*NK*NK; i += 256) {
    int m = i >> 8, k = (i >> 4) & 15, j = i & 15;
    float acc = 0.f;
    #pragma unroll
    for (int r = 0; r < NR; r++) acc += U[(m*NK+k)*NR + r]*U[(m*NK+j)*NR + r];
    Gs[i] = acc;
  }
  __syncthreads();
  for (int i = t; i < NM*NK; i += 256) {
    float s = 0.f;
    #pragma unroll
    for (int j = 0; j < NK; j++) s += Gs[i*NK + j];
    rs[i] = fmaxf(s, 1e-8f);
  }
  __syncthreads();
  for (int i = t; i < NM*NK*NK; i += 256) { Gs[i] /= rs[i >> 4]; G[i] = Gs[i]; }
  __syncthreads();
  for (int i = t; i < NM; i += 256) {
    float s = 0.f;
    for (int j = 0; j < NK*NK; j++) { float g = Gs[i*NK*NK + j]; s += g*g; }
    vn[i] = fmaxf(sqrtf(s), 1e-8f);
  }
  __syncthreads();
  for (int i = t; i < NM*NM; i += 256) {
    int a = i >> 3, b = i & 7;
    float s = 0.f;
    for (int j = 0; j < NK*NK; j++) s += Gs[a*NK*NK + j]*Gs[b*NK*NK + j];
    gram[i] = s / (vn[a]*vn[b]);
  }
  __syncthreads();
  if (t == 0) {
    float s = 0.f;
    for (int i = 0; i < NM*NM; i++) if ((i >> 3) != (i & 7)) s += gram[i];
    greg[0] = 0.1f * s / (float)(NM*(NM-1));
  }
  for (int i = t; i < NM*NK*NK; i += 256) {
    int m = i >> 8, k = (i >> 4) & 15, j = i & 15;
    float dk = fmaxf(Gs[m*NK*NK + k*NK + k], 1e-8f);
    float dj = fmaxf(Gs[m*NK*NK + j*NK + j], 1e-8f);
    float den = fmaxf(sqrtf(dk*dj), 1e-8f);
    float c = fminf(fmaxf(Gs[i]/den, -1.f), 1.f);
    float d = fmaxf(1.f - c, 0.f);
    if (k == j) d = 0.f;
    DG[i] = d;
  }
}

// ---------------- Pi init ----------------
__global__ void k_fillpi(float* __restrict__ Pi) {
  int idx = blockIdx.x*256 + threadIdx.x;
  Pi[idx] = 1.f / (float)(NN*NK);
}

// ---------------- marginals ----------------
__global__ void k_mass(const float* __restrict__ Pi, float* __restrict__ massj,
                       float* __restrict__ massl) {
  int bhm = blockIdx.x;
  const float* Pb = Pi + (size_t)bhm*SLAB;
  __shared__ float red[256][17];
  int t = threadIdx.x;
  float accl[NK];
  #pragma unroll
  for (int k = 0; k < NK; k++) accl[k] = 0.f;
  #pragma unroll
  for (int i = 0; i < 2; i++) {
    int n = t + i*256;
    float s = 0.f;
    #pragma unroll
    for (int k = 0; k < NK; k++) { float p = Pb[n*NK + k]; s += p; accl[k] += p; }
    massj[bhm*NN + n] = s;
  }
  #pragma unroll
  for (int k = 0; k < NK; k++) red[t][k] = accl[k];
  __syncthreads();
  for (int s = 128; s > 0; s >>= 1) {
    if (t < s) { for (int k = 0; k < NK; k++) red[t][k] += red[t+s][k]; }
    __syncthreads();
  }
  if (t < NK) massl[bhm*NK + t] = red[0][t];
}

// ---------------- term2 ----------------
__global__ void k_term2(const float* __restrict__ DG, const float* __restrict__ massl,
                        float* __restrict__ term2) {
  int idx = blockIdx.x*256 + threadIdx.x;
  if (idx >= BHM*NK) return;
  int k = idx & 15, bhm = idx >> 4;
  int m = bhm & 7;
  float s = 0.f;
  #pragma unroll
  for (int l = 0; l < NK; l++) { float d = DG[(m*NK + k)*NK + l]; s += d*d*massl[bhm*NK + l]; }
  term2[idx] = s;
}

// ---------------- cost: all 8 m per block, term1 fused ----------------
__global__ __launch_bounds__(256) void k_cost(const float* __restrict__ DPm, const float* __restrict__ Pi,
                       const float* __restrict__ DG, const float* __restrict__ massj,
                       const float* __restrict__ term2, float* __restrict__ C,
                       float* __restrict__ Km) {
  int blk = blockIdx.x;          // 64 bh * 16 itiles
  int it = blk & 15, bh = blk >> 4;
  int i0 = it*32;
  __shared__ float mjs[8][516];
  __shared__ float dgs[8][16][17];
  __shared__ float t2s[8][16];
  __shared__ float dps[32][36];
  __shared__ float pjs[8][33][20];
  int t = threadIdx.x;
  {
    int m = t >> 5, jq = (t & 31)*4;
    for (int qq = 0; qq < 4; qq++) {
      int j = jq + 128*qq;
      float4 v = *(const float4*)(massj + ((size_t)(bh*8+m))*NN + j);
      *(float4*)&mjs[m][j] = v;
    }
  }
  for (int f = t; f < NM*NK*NK; f += 256) {
    dgs[f >> 8][(f >> 4) & 15][f & 15] = DG[f];
  }
  if (t < 128) t2s[t >> 4][t & 15] = term2[bh*128 + t];
  int li = t >> 3;    // local i 0..31
  int m  = t & 7;
  float w[16];
  #pragma unroll
  for (int k = 0; k < 16; k++) w[k] = 0.f;
  float t1 = 0.f;
  __syncthreads();
  for (int j0 = 0; j0 < NN; j0 += 32) {
    {
      int r = t >> 3, jq = (t & 7)*4;
      float4 v = *(const float4*)(DPm + ((size_t)(bh*NN) + i0 + r)*NN + j0 + jq);
      *(float4*)&dps[r][jq] = v;
    }
    {
      int mm = t >> 5, jj = t & 31;
      const float* src = Pi + ((size_t)(bh*8+mm))*SLAB + (size_t)(j0+jj)*16;
      float4 v0 = *(const float4*)(src);
      float4 v1 = *(const float4*)(src+4);
      float4 v2 = *(const float4*)(src+8);
      float4 v3 = *(const float4*)(src+12);
      *(float4*)&pjs[mm][jj][0]  = v0;
      *(float4*)&pjs[mm][jj][4]  = v1;
      *(float4*)&pjs[mm][jj][8]  = v2;
      *(float4*)&pjs[mm][jj][12] = v3;
    }
    __syncthreads();
    #pragma unroll 4
    for (int jj = 0; jj < 32; jj++) {
      float dp = dps[li][jj];
      t1 += dp*dp*mjs[m][j0+jj];
      float4 p0 = *(const float4*)&pjs[m][jj][0];
      float4 p1 = *(const float4*)&pjs[m][jj][4];
      float4 p2 = *(const float4*)&pjs[m][jj][8];
      float4 p3 = *(const float4*)&pjs[m][jj][12];
      w[0]  += dp*p0.x; w[1]  += dp*p0.y; w[2]  += dp*p0.z; w[3]  += dp*p0.w;
      w[4]  += dp*p1.x; w[5]  += dp*p1.y; w[6]  += dp*p1.z; w[7]  += dp*p1.w;
      w[8]  += dp*p2.x; w[9]  += dp*p2.y; w[10] += dp*p2.z; w[11] += dp*p2.w;
      w[12] += dp*p3.x; w[13] += dp*p3.y; w[14] += dp*p3.z; w[15] += dp*p3.w;
    }
    __syncthreads();
  }
  int bhm = bh*8 + m;
  float cb[16];
  #pragma unroll
  for (int k = 0; k < 16; k++) {
    float cr2 = 0.f;
    #pragma unroll
    for (int l = 0; l < 16; l++) cr2 += w[l]*dgs[m][k][l];
    cb[k] = fmaxf(t1 + t2s[m][k] - 2.f*cr2, 0.f);
  }
  float* Cb = C  + (size_t)bhm*SLAB + (size_t)(i0+li)*16;
  float* Kb = Km + (size_t)bhm*SLAB + (size_t)(i0+li)*16;
  #pragma unroll
  for (int q = 0; q < 4; q++) {
    float4 co; co.x = cb[q*4]; co.y = cb[q*4+1]; co.z = cb[q*4+2]; co.w = cb[q*4+3];
    *(float4*)(Cb + q*4) = co;
    float4 ko;
    ko.x = fmaxf(expf(-20.f*co.x), 1e-12f);
    ko.y = fmaxf(expf(-20.f*co.y), 1e-12f);
    ko.z = fmaxf(expf(-20.f*co.z), 1e-12f);
    ko.w = fmaxf(expf(-20.f*co.w), 1e-12f);
    *(float4*)(Kb + q*4) = ko;
  }
}

// ---------------- sinkhorn (10 iters fused) ----------------
__global__ void k_sinkhorn(const float* __restrict__ Km, float* __restrict__ Pi) {
  int bhm = blockIdx.x;
  const float* Kb = Km + (size_t)bhm*SLAB;
  __shared__ float KT[NK][NN+1];
  __shared__ float u[NN];
  __shared__ float v[NK];
  __shared__ float red[256][17];
  int t = threadIdx.x;
  for (int i = t; i < SLAB; i += 256) KT[i & 15][i >> 4] = Kb[i];
  if (t < NK) v[t] = 1.f/16.f;
  __syncthreads();
  for (int it = 0; it < 10; ++it) {
    #pragma unroll
    for (int i = 0; i < 2; i++) {
      int n = t + i*256;
      float s = 0.f;
      #pragma unroll
      for (int k = 0; k < NK; k++) s += KT[k][n]*v[k];
      u[n] = (1.f/512.f)/(s + 1e-6f);
    }
    __syncthreads();
    float accl[NK];
    #pragma unroll
    for (int k = 0; k < NK; k++) accl[k] = 0.f;
    #pragma unroll
    for (int i = 0; i < 2; i++) {
      int n = t + i*256; float un = u[n];
      #pragma unroll
      for (int k = 0; k < NK; k++) accl[k] += KT[k][n]*un;
    }
    #pragma unroll
    for (int k = 0; k < NK; k++) red[t][k] = accl[k];
    __syncthreads();
    for (int s = 128; s > 0; s >>= 1) {
      if (t < s) { for (int k = 0; k < NK; k++) red[t][k] += red[t+s][k]; }
      __syncthreads();
    }
    if (t < NK) v[t] = (1.f/16.f)/(red[0][t] + 1e-6f);
    __syncthreads();
  }
  float* Pib = Pi + (size_t)bhm*SLAB;
  for (int i = t; i < SLAB; i += 256) {
    int n = i >> 4, k = i & 15;
    Pib[i] = u[n]*KT[k][n]*v[k];
  }
}

// ---------------- gw_val ----------------
__global__ void k_gwval(const float* __restrict__ C, const float* __restrict__ Pi,
                        float* __restrict__ gw) {
  int bhm = blockIdx.x; int t = threadIdx.x;
  __shared__ float red[256];
  const float* Cb = C + (size_t)bhm*SLAB;
  const float* Pb = Pi + (size_t)bhm*SLAB;
  float s = 0.f;
  for (int i = t; i < SLAB; i += 256) s += Cb[i]*Pb[i];
  red[t] = s; __syncthreads();
  for (int q = 128; q > 0; q >>= 1) { if (t < q) red[t] += red[t+q]; __syncthreads(); }
  if (t == 0) gw[bhm] = red[0];
}

// ---------------- alpha ----------------
__global__ void k_alpha(const float* __restrict__ gw, float* __restrict__ alpha) {
  int t = threadIdx.x;
  float g = gw[t];
  float sc = expf(-(g*g));
  float s = sc;
  s += __shfl_xor(s, 1); s += __shfl_xor(s, 2); s += __shfl_xor(s, 4);
  alpha[t] = sc / fmaxf(s, 1e-8f);
}

// ---------------- Qmix ----------------
__global__ void k_qmix(const float* __restrict__ Pi, const float* __restrict__ G,
                       const float* __restrict__ alpha, float* __restrict__ Qraw) {
  int blk = blockIdx.x;             // 64*16*16
  int st = blk & 15;
  int nt = (blk >> 4) & 15;
  int bh = blk >> 8;
  __shared__ float Pn[32][17], Ps[32][17], Gs[16][16], Tn[32][17];
  int t = threadIdx.x;
  int ii = t >> 5;
  int ss = t & 31;
  float acc[4] = {0.f, 0.f, 0.f, 0.f};
  for (int m = 0; m < NM; m++) {
    const float* Pib = Pi + ((size_t)(bh*NM + m))*SLAB;
    #pragma unroll
    for (int q = 0; q < 2; q++) {
      int idx = t + q*256;
      Pn[idx >> 4][idx & 15] = Pib[nt*512 + idx];
      Ps[idx >> 4][idx & 15] = Pib[st*512 + idx];
    }
    Gs[t >> 4][t & 15] = G[m*NK*NK + t];
    __syncthreads();
    #pragma unroll
    for (int q = 0; q < 2; q++) {
      int idx = t + q*256;
      int i = idx >> 4, l = idx & 15;
      float s2 = 0.f;
      #pragma unroll
      for (int k = 0; k < NK; k++) s2 += Pn[i][k]*Gs[k][l];
      Tn[i][l] = s2;
    }
    __syncthreads();
    float al = alpha[bh*NM + m];
    #pragma unroll
    for (int q = 0; q < 4; q++) {
      int i = ii + q*8;
      float s2 = 0.f;
      #pragma unroll
      for (int l = 0; l < NK; l++) s2 += Tn[i][l]*Ps[ss][l];
      acc[q] += al*s2;
    }
    __syncthreads();
  }
  float* Qb = Qraw + (size_t)bh*NN*NN;
  #pragma unroll
  for (int q = 0; q < 4; q++) {
    int i = nt*32 + ii + q*8;
    int s = st*32 + ss;
    Qb[(size_t)i*NN + s] = acc[q];
  }
}

// ---------------- normalize Q + bias_log ----------------
__global__ void k_qnorm(float* __restrict__ out) {
  int bhn = blockIdx.x;
  int t = threadIdx.x;
  float* Qrow = out + (size_t)16777216 + (size_t)bhn*NN;
  float* Brow = out + (size_t)bhn*NN;
  __shared__ float red[256];
  float q0 = fmaxf(Qrow[t], 1e-8f), q1 = fmaxf(Qrow[t+256], 1e-8f);
  red[t] = q0 + q1; __syncthreads();
  for (int s = 128; s > 0; s >>= 1) { if (t < s) red[t] += red[t+s]; __syncthreads(); }
  float inv = 1.f / red[0];
  float a = q0*inv, b = q1*inv;
  Qrow[t] = a; Qrow[t+256] = b;
  Brow[t] = logf(a); Brow[t+256] = logf(b);
}

// ---------------- slot usage: thread-per-row, block partials ----------------
__global__ __launch_bounds__(256) void k_usage(const float* __restrict__ z, const float* __restrict__ Wp,
                        const float* __restrict__ bp, float* __restrict__ partial) {
  __shared__ float wps[256][9];
  __shared__ float red[256][8];
  int t = threadIdx.x;
  {
    float4 a = *(const float4*)(Wp + t*8);
    float4 b = *(const float4*)(Wp + t*8 + 4);
    wps[t][0]=a.x; wps[t][1]=a.y; wps[t][2]=a.z; wps[t][3]=a.w;
    wps[t][4]=b.x; wps[t][5]=b.y; wps[t][6]=b.z; wps[t][7]=b.w;
  }
  __syncthreads();
  int row = blockIdx.x*256 + t;
  const float* zr = z + (size_t)row*ND;
  float acc[8] = {};
  for (int d0 = 0; d0 < ND; d0 += 4) {
    float4 v = *(const float4*)(zr + d0);
    #pragma unroll
    for (int m = 0; m < 8; m++) {
      acc[m] += v.x*wps[d0][m] + v.y*wps[d0+1][m] + v.z*wps[d0+2][m] + v.w*wps[d0+3][m];
    }
  }
  float mx = -1e30f;
  #pragma unroll
  for (int m = 0; m < 8; m++) { acc[m] += bp[m]; mx = fmaxf(mx, acc[m]); }
  float s = 0.f;
  #pragma unroll
  for (int m = 0; m < 8; m++) { acc[m] = expf(acc[m]-mx); s += acc[m]; }
  float inv = 1.f/s;
  #pragma unroll
  for (int m = 0; m < 8; m++) red[t][m] = acc[m]*inv;
  __syncthreads();
  for (int q = 128; q > 0; q >>= 1) {
    if (t < q) { for (int m = 0; m < 8; m++) red[t][m] += red[t+q][m]; }
    __syncthreads();
  }
  if (t < 8) partial[blockIdx.x*8 + t] = red[0][t];
}

// ---------------- final scalar ----------------
__global__ void k_final(const float* __restrict__ greg, const float* __restrict__ partial,
                        float* __restrict__ out) {
  if (threadIdx.x == 0) {
    float us[8] = {};
    for (int b = 0; b < 16; b++)
      for (int m = 0; m < 8; m++) us[m] += partial[b*8 + m];
    float kl = 0.f;
    for (int m = 0; m < 8; m++) {
      float u = us[m] / (float)BN;
      kl += u*logf(fmaxf(u, 1e-8f)*(float)NM);
    }
    out[33554432] = greg[0] + 0.01f*kl;
  }
}

extern "C" void kernel_launch(void* const* d_in, const int* in_sizes, int n_in,
                              void* d_out, int out_size, void* d_ws, size_t ws_size,
                              hipStream_t stream) {
  const float* xd = (const float*)d_in[0];
  const float* xn = (const float*)d_in[1];
  const float* W1 = (const float*)d_in[2];
  const float* b1 = (const float*)d_in[3];
  const float* W2 = (const float*)d_in[4];
  const float* b2 = (const float*)d_in[5];
  const float* Wp = (const float*)d_in[6];
  const float* bp = (const float*)d_in[7];
  const float* Up = (const float*)d_in[8];
  float* out = (float*)d_out;
  float* ws  = (float*)d_ws;

  float* z     = ws + 0;
  float* hid   = ws + 1048576;
  float* zh    = ws + 2097152;
  float* Pi    = ws + 3145728;
  float* C     = ws + 7340032;
  float* Km    = ws + 11534336;
  float* massj = ws + 15728640;
  float* partial = ws + 15990784;   // 128 floats (reuses old term1 slot)
  float* massl = ws + 16252928;
  float* term2 = ws + 16261120;
  float* gw    = ws + 16269312;
  float* alpha = ws + 16269824;
  float* G     = ws + 16270336;
  float* DG    = ws + 16272384;
  float* greg  = ws + 16274432;

  float* P  = out;                  // scratch in bias region
  float* DP = out + 16777216;       // scratch in Q region

  k_mlp1<<<dim3(4, 64), 256, 0, stream>>>(xd, xn, W1, b1, hid);
  k_mlp2<<<dim3(4, 64), 256, 0, stream>>>(hid, W2, b2, z);
  k_zhnorm<<<4096, 256, 0, stream>>>(z, zh);
  k_affinity<<<1024, 256, 0, stream>>>(zh, P);
  k_dp<<<1024, 256, 0, stream>>>(P, DP);
  k_slots<<<1, 256, 0, stream>>>(Up, G, DG, greg);
  k_fillpi<<<16384, 256, 0, stream>>>(Pi);
  for (int it = 0; it < 3; ++it) {
    k_mass<<<BHM, 256, 0, stream>>>(Pi, massj, massl);
    k_term2<<<32, 256, 0, stream>>>(DG, massl, term2);
    k_cost<<<1024, 256, 0, stream>>>(DP, Pi, DG, massj, term2, C, Km);
    k_sinkhorn<<<BHM, 256, 0, stream>>>(Km, Pi);
  }
  k_gwval<<<BHM, 256, 0, stream>>>(C, Pi, gw);
  k_alpha<<<1, 512, 0, stream>>>(gw, alpha);
  k_qmix<<<16384, 256, 0, stream>>>(Pi, G, alpha, out + 16777216);
  k_qnorm<<<BHN, 256, 0, stream>>>(out);
  k_usage<<<16, 256, 0, stream>>>(z, Wp, bp, partial);
  k_final<<<1, 64, 0, stream>>>(greg, partial, out);
}

// Round 3
// 771.488 us; speedup vs baseline: 3.3212x; 1.4726x over previous
//
#include <hip/hip_runtime.h>
#include <cstdint>
#include <cstddef>

#define NB 8
#define NN 512
#define ND 256
#define NH 8
#define NM 8
#define NK 16
#define NR 8
#define NDH 32
#define BN (NB*NN)           // 4096 rows
#define BH (NB*NH)           // 64
#define BHN (BH*NN)          // 32768
#define BHM (BH*NM)          // 512
#define SLAB (NN*NK)         // 8192
#define QOFF 16777216        // B*H*N*N

typedef __attribute__((ext_vector_type(8))) short bf16x8;
typedef __attribute__((ext_vector_type(8))) unsigned short u16x8;
typedef __attribute__((ext_vector_type(4))) float f32x4;

__device__ inline unsigned short f2bf(float x) {
  union { float f; unsigned u; } c; c.f = x;
  unsigned r = c.u + 0x7FFFu + ((c.u >> 16) & 1u);
  return (unsigned short)(r >> 16);
}

// ---------------- MLP: 64x64 tile, 4x4 per thread ----------------
__global__ __launch_bounds__(256) void k_mlp1(const float* __restrict__ xd, const float* __restrict__ xn,
                       const float* __restrict__ W1, const float* __restrict__ b1,
                       float* __restrict__ hid) {
  __shared__ float As[16][68];   // [k][i]
  __shared__ float Bs[16][68];   // [k][j]
  int t = threadIdx.x;
  int col0 = blockIdx.x * 64;
  int row0 = blockIdx.y * 64;
  int ar = t >> 2, ak = (t & 3) * 4;
  int bk = t >> 4, bc = (t & 15) * 4;
  int ty = t >> 4, tx = t & 15;
  float acc[4][4] = {};
  for (int k0 = 0; k0 < 2*ND; k0 += 16) {
    int gk = k0 + ak;
    const float* src = (gk < ND) ? (xd + (size_t)(row0+ar)*ND + gk)
                                 : (xn + (size_t)(row0+ar)*ND + (gk-ND));
    float4 av = *(const float4*)src;
    As[ak+0][ar] = av.x; As[ak+1][ar] = av.y; As[ak+2][ar] = av.z; As[ak+3][ar] = av.w;
    float4 bv = *(const float4*)(W1 + (size_t)(k0+bk)*ND + col0 + bc);
    *(float4*)&Bs[bk][bc] = bv;
    __syncthreads();
    #pragma unroll
    for (int kk = 0; kk < 16; kk++) {
      float4 a = *(const float4*)&As[kk][ty*4];
      float4 b = *(const float4*)&Bs[kk][tx*4];
      acc[0][0] += a.x*b.x; acc[0][1] += a.x*b.y; acc[0][2] += a.x*b.z; acc[0][3] += a.x*b.w;
      acc[1][0] += a.y*b.x; acc[1][1] += a.y*b.y; acc[1][2] += a.y*b.z; acc[1][3] += a.y*b.w;
      acc[2][0] += a.z*b.x; acc[2][1] += a.z*b.y; acc[2][2] += a.z*b.z; acc[2][3] += a.z*b.w;
      acc[3][0] += a.w*b.x; acc[3][1] += a.w*b.y; acc[3][2] += a.w*b.z; acc[3][3] += a.w*b.w;
    }
    __syncthreads();
  }
  float4 bb = *(const float4*)(b1 + col0 + tx*4);
  #pragma unroll
  for (int a = 0; a < 4; a++) {
    float4 o;
    o.x = fmaxf(acc[a][0] + bb.x, 0.f);
    o.y = fmaxf(acc[a][1] + bb.y, 0.f);
    o.z = fmaxf(acc[a][2] + bb.z, 0.f);
    o.w = fmaxf(acc[a][3] + bb.w, 0.f);
    *(float4*)(hid + (size_t)(row0+ty*4+a)*ND + col0 + tx*4) = o;
  }
}

__global__ __launch_bounds__(256) void k_mlp2(const float* __restrict__ hidp,
                       const float* __restrict__ W2, const float* __restrict__ b2,
                       float* __restrict__ z) {
  __shared__ float As[16][68];
  __shared__ float Bs[16][68];
  int t = threadIdx.x;
  int col0 = blockIdx.x * 64;
  int row0 = blockIdx.y * 64;
  int ar = t >> 2, ak = (t & 3) * 4;
  int bk = t >> 4, bc = (t & 15) * 4;
  int ty = t >> 4, tx = t & 15;
  float acc[4][4] = {};
  for (int k0 = 0; k0 < ND; k0 += 16) {
    float4 av = *(const float4*)(hidp + (size_t)(row0+ar)*ND + k0 + ak);
    As[ak+0][ar] = av.x; As[ak+1][ar] = av.y; As[ak+2][ar] = av.z; As[ak+3][ar] = av.w;
    float4 bv = *(const float4*)(W2 + (size_t)(k0+bk)*ND + col0 + bc);
    *(float4*)&Bs[bk][bc] = bv;
    __syncthreads();
    #pragma unroll
    for (int kk = 0; kk < 16; kk++) {
      float4 a = *(const float4*)&As[kk][ty*4];
      float4 b = *(const float4*)&Bs[kk][tx*4];
      acc[0][0] += a.x*b.x; acc[0][1] += a.x*b.y; acc[0][2] += a.x*b.z; acc[0][3] += a.x*b.w;
      acc[1][0] += a.y*b.x; acc[1][1] += a.y*b.y; acc[1][2] += a.y*b.z; acc[1][3] += a.y*b.w;
      acc[2][0] += a.z*b.x; acc[2][1] += a.z*b.y; acc[2][2] += a.z*b.z; acc[2][3] += a.z*b.w;
      acc[3][0] += a.w*b.x; acc[3][1] += a.w*b.y; acc[3][2] += a.w*b.z; acc[3][3] += a.w*b.w;
    }
    __syncthreads();
  }
  float4 bb = *(const float4*)(b2 + col0 + tx*4);
  #pragma unroll
  for (int a = 0; a < 4; a++) {
    float4 o;
    o.x = acc[a][0] + bb.x; o.y = acc[a][1] + bb.y;
    o.z = acc[a][2] + bb.z; o.w = acc[a][3] + bb.w;
    *(float4*)(z + (size_t)(row0+ty*4+a)*ND + col0 + tx*4) = o;
  }
}

// ---------------- zh normalize ----------------
__global__ void k_zhnorm(const float* __restrict__ z, float* __restrict__ zh) {
  int idx = blockIdx.x*256 + threadIdx.x;
  int d = idx & 31;
  int n = (idx >> 5) & (NN-1);
  int h = (idx >> 14) & (NH-1);
  int b = idx >> 17;
  float v = z[(size_t)(b*NN + n)*ND + h*NDH + d];
  float ss = v*v;
  #pragma unroll
  for (int m = 1; m < 32; m <<= 1) ss += __shfl_xor(ss, m);
  zh[idx] = v / fmaxf(sqrtf(ss), 1e-8f);
}

// ---------------- affinity + softmax -> P ----------------
__global__ __launch_bounds__(256) void k_affinity(const float* __restrict__ zh, float* __restrict__ P) {
  int blk = blockIdx.x;               // 64 bh * 16 rowtiles
  int rt = blk & 15, bh = blk >> 4;
  int r0 = rt*32;
  const float* base = zh + (size_t)bh*NN*NDH;
  __shared__ float qs[32][33];
  __shared__ float ks[32][36];        // [d][s]
  int t = threadIdx.x;
  int sr = t >> 3, dq = (t & 7)*4;
  {
    float4 v = *(const float4*)(base + (size_t)(r0+sr)*NDH + dq);
    qs[sr][dq] = v.x; qs[sr][dq+1] = v.y; qs[sr][dq+2] = v.z; qs[sr][dq+3] = v.w;
  }
  int cr = t >> 3;
  int cq = t & 7;
  float acc[16][4];
  #pragma unroll
  for (int ti = 0; ti < 16; ti++) { acc[ti][0]=0; acc[ti][1]=0; acc[ti][2]=0; acc[ti][3]=0; }
  for (int ti = 0; ti < 16; ti++) {
    int s0 = ti*32;
    __syncthreads();
    {
      float4 v = *(const float4*)(base + (size_t)(s0+sr)*NDH + dq);
      ks[dq+0][sr] = v.x; ks[dq+1][sr] = v.y; ks[dq+2][sr] = v.z; ks[dq+3][sr] = v.w;
    }
    __syncthreads();
    #pragma unroll
    for (int d = 0; d < 32; d++) {
      float qv = qs[cr][d];
      float4 kv = *(const float4*)&ks[d][cq*4];
      acc[ti][0] += qv*kv.x; acc[ti][1] += qv*kv.y;
      acc[ti][2] += qv*kv.z; acc[ti][3] += qv*kv.w;
    }
  }
  int gr = r0 + cr;
  float mx = -1e30f;
  #pragma unroll
  for (int ti = 0; ti < 16; ti++) {
    #pragma unroll
    for (int j = 0; j < 4; j++) {
      int s = ti*32 + cq*4 + j;
      float v = (s == gr) ? -1e9f : acc[ti][j]*0.0625f;
      acc[ti][j] = v;
      mx = fmaxf(mx, v);
    }
  }
  mx = fmaxf(mx, __shfl_xor(mx, 1));
  mx = fmaxf(mx, __shfl_xor(mx, 2));
  mx = fmaxf(mx, __shfl_xor(mx, 4));
  float sum = 0.f;
  #pragma unroll
  for (int ti = 0; ti < 16; ti++) {
    #pragma unroll
    for (int j = 0; j < 4; j++) { float e = expf(acc[ti][j]-mx); acc[ti][j] = e; sum += e; }
  }
  sum += __shfl_xor(sum,1); sum += __shfl_xor(sum,2); sum += __shfl_xor(sum,4);
  float inv = 1.f/sum;
  float* prow = P + ((size_t)(bh*NN) + gr)*NN;
  #pragma unroll
  for (int ti = 0; ti < 16; ti++) {
    float4 o; o.x = acc[ti][0]*inv; o.y = acc[ti][1]*inv; o.z = acc[ti][2]*inv; o.w = acc[ti][3]*inv;
    *(float4*)(prow + ti*32 + cq*4) = o;
  }
}

// ---------------- DP: symmetrize + row-normalize ----------------
__global__ __launch_bounds__(256) void k_dp(const float* __restrict__ P, float* __restrict__ DPo) {
  int blk = blockIdx.x;               // 64*16
  int rt = blk & 15, bh = blk >> 4;
  int r0 = rt*32;
  const float* Pb = P + (size_t)bh*NN*NN;
  __shared__ float Bs[32][33];
  int t = threadIdx.x;
  int r = t >> 3, q4 = (t & 7)*4;
  float pn[16][4];
  float rowacc = 0.f;
  for (int ti = 0; ti < 16; ti++) {
    int s0 = ti*32;
    __syncthreads();
    {
      float4 v = *(const float4*)(Pb + (size_t)(s0+r)*NN + r0 + q4);
      Bs[r][q4] = v.x; Bs[r][q4+1] = v.y; Bs[r][q4+2] = v.z; Bs[r][q4+3] = v.w;
    }
    float4 a = *(const float4*)(Pb + (size_t)(r0+r)*NN + s0 + q4);
    __syncthreads();
    float p0 = fmaxf(0.5f*(a.x + Bs[q4+0][r]), 1e-8f);
    float p1 = fmaxf(0.5f*(a.y + Bs[q4+1][r]), 1e-8f);
    float p2 = fmaxf(0.5f*(a.z + Bs[q4+2][r]), 1e-8f);
    float p3 = fmaxf(0.5f*(a.w + Bs[q4+3][r]), 1e-8f);
    pn[ti][0]=p0; pn[ti][1]=p1; pn[ti][2]=p2; pn[ti][3]=p3;
    rowacc += p0+p1+p2+p3;
  }
  rowacc += __shfl_xor(rowacc,1); rowacc += __shfl_xor(rowacc,2); rowacc += __shfl_xor(rowacc,4);
  float inv = 1.f / fmaxf(rowacc, 1e-8f);
  float* drow = DPo + ((size_t)(bh*NN) + r0 + r)*NN;
  #pragma unroll
  for (int ti = 0; ti < 16; ti++) {
    float4 o;
    o.x = fmaxf(1.f - pn[ti][0]*inv, 0.f);
    o.y = fmaxf(1.f - pn[ti][1]*inv, 0.f);
    o.z = fmaxf(1.f - pn[ti][2]*inv, 0.f);
    o.w = fmaxf(1.f - pn[ti][3]*inv, 0.f);
    *(float4*)(drow + ti*32 + q4) = o;
  }
}

// ---------------- slot graphs: G, g_reg, DG ----------------
__global__ void k_slots(const float* __restrict__ Up, float* __restrict__ G,
                        float* __restrict__ DG, float* __restrict__ greg) {
  __shared__ float U[NM*NK*NR];
  __shared__ float Gs[NM*NK*NK];
  __shared__ float rs[NM*NK];
  __shared__ float vn[NM];
  __shared__ float gram[NM*NM];
  int t = threadIdx.x;
  for (int i = t; i < NM*NK*NR; i += 256) {
    float x = Up[i];
    U[i] = fmaxf(x, 0.f) + log1pf(expf(-fabsf(x)));
  }
  __syncthreads();
  for (int i = t; i < NM*NK*NK; i += 256) {
    int m = i >> 8, k = (i >> 4) & 15, j = i & 15;
    float acc = 0.f;
    #pragma unroll
    for (int r = 0; r < NR; r++) acc += U[(m*NK+k)*NR + r]*U[(m*NK+j)*NR + r];
    Gs[i] = acc;
  }
  __syncthreads();
  for (int i = t; i < NM*NK; i += 256) {
    float s = 0.f;
    #pragma unroll
    for (int j = 0; j < NK; j++) s += Gs[i*NK + j];
    rs[i] = fmaxf(s, 1e-8f);
  }
  __syncthreads();
  for (int i = t; i < NM*NK*NK; i += 256) { Gs[i] /= rs[i >> 4]; G[i] = Gs[i]; }
  __syncthreads();
  for (int i = t; i < NM; i += 256) {
    float s = 0.f;
    for (int j = 0; j < NK*NK; j++) { float g = Gs[i*NK*NK + j]; s += g*g; }
    vn[i] = fmaxf(sqrtf(s), 1e-8f);
  }
  __syncthreads();
  for (int i = t; i < NM*NM; i += 256) {
    int a = i >> 3, b = i & 7;
    float s = 0.f;
    for (int j = 0; j < NK*NK; j++) s += Gs[a*NK*NK + j]*Gs[b*NK*NK + j];
    gram[i] = s / (vn[a]*vn[b]);
  }
  __syncthreads();
  if (t == 0) {
    float s = 0.f;
    for (int i = 0; i < NM*NM; i++) if ((i >> 3) != (i & 7)) s += gram[i];
    greg[0] = 0.1f * s / (float)(NM*(NM-1));
  }
  for (int i = t; i < NM*NK*NK; i += 256) {
    int m = i >> 8, k = (i >> 4) & 15, j = i & 15;
    float dk = fmaxf(Gs[m*NK*NK + k*NK + k], 1e-8f);
    float dj = fmaxf(Gs[m*NK*NK + j*NK + j], 1e-8f);
    float den = fmaxf(sqrtf(dk*dj), 1e-8f);
    float c = fminf(fmaxf(Gs[i]/den, -1.f), 1.f);
    float d = fmaxf(1.f - c, 0.f);
    if (k == j) d = 0.f;
    DG[i] = d;
  }
}

// ---------------- marginals ----------------
__global__ void k_mass(const float* __restrict__ Pi, float* __restrict__ massj,
                       float* __restrict__ massl) {
  int bhm = blockIdx.x;
  const float* Pb = Pi + (size_t)bhm*SLAB;
  __shared__ float red[256][17];
  int t = threadIdx.x;
  float accl[NK];
  #pragma unroll
  for (int k = 0; k < NK; k++) accl[k] = 0.f;
  #pragma unroll
  for (int i = 0; i < 2; i++) {
    int n = t + i*256;
    float s = 0.f;
    #pragma unroll
    for (int k = 0; k < NK; k++) { float p = Pb[n*NK + k]; s += p; accl[k] += p; }
    massj[bhm*NN + n] = s;
  }
  #pragma unroll
  for (int k = 0; k < NK; k++) red[t][k] = accl[k];
  __syncthreads();
  for (int s = 128; s > 0; s >>= 1) {
    if (t < s) { for (int k = 0; k < NK; k++) red[t][k] += red[t+s][k]; }
    __syncthreads();
  }
  if (t < NK) massl[bhm*NK + t] = red[0][t];
}

// ---------------- term2 ----------------
__global__ void k_term2(const float* __restrict__ DG, const float* __restrict__ massl,
                        float* __restrict__ term2) {
  int idx = blockIdx.x*256 + threadIdx.x;
  if (idx >= BHM*NK) return;
  int k = idx & 15, bhm = idx >> 4;
  int m = bhm & 7;
  float s = 0.f;
  #pragma unroll
  for (int l = 0; l < NK; l++) { float d = DG[(m*NK + k)*NK + l]; s += d*d*massl[bhm*NK + l]; }
  term2[idx] = s;
}

// term2 for uniform Pi: massl = 1/16
__global__ void k_term2u(const float* __restrict__ DG, float* __restrict__ term2) {
  int idx = blockIdx.x*256 + threadIdx.x;
  if (idx >= BHM*NK) return;
  int k = idx & 15, bhm = idx >> 4;
  int m = bhm & 7;
  float s = 0.f;
  #pragma unroll
  for (int l = 0; l < NK; l++) { float d = DG[(m*NK + k)*NK + l]; s += d*d; }
  term2[idx] = s * (1.f/16.f);
}

// ---------------- cost: all 8 m per block, term1 fused ----------------
template<int UNIF>
__global__ __launch_bounds__(256) void k_cost(const float* __restrict__ DPm, const float* __restrict__ Pi,
                       const float* __restrict__ DG, const float* __restrict__ massj,
                       const float* __restrict__ term2, float* __restrict__ C,
                       float* __restrict__ Km) {
  int blk = blockIdx.x;          // 64 bh * 16 itiles
  int it = blk & 15, bh = blk >> 4;
  int i0 = it*32;
  __shared__ float mjs[8][516];
  __shared__ float dgs[8][16][17];
  __shared__ float t2s[8][16];
  __shared__ float dps[32][36];
  __shared__ float pjs[8][33][20];
  int t = threadIdx.x;
  if (!UNIF) {
    int m = t >> 5, jq = (t & 31)*4;
    for (int qq = 0; qq < 4; qq++) {
      int j = jq + 128*qq;
      float4 v = *(const float4*)(massj + ((size_t)(bh*8+m))*NN + j);
      *(float4*)&mjs[m][j] = v;
    }
  }
  for (int f = t; f < NM*NK*NK; f += 256) {
    dgs[f >> 8][(f >> 4) & 15][f & 15] = DG[f];
  }
  if (t < 128) t2s[t >> 4][t & 15] = term2[bh*128 + t];
  int li = t >> 3;    // local i 0..31
  int m  = t & 7;
  float w[16];
  #pragma unroll
  for (int k = 0; k < 16; k++) w[k] = 0.f;
  float t1 = 0.f;
  float rsum = 0.f, t1a = 0.f;
  __syncthreads();
  for (int j0 = 0; j0 < NN; j0 += 32) {
    {
      int r = t >> 3, jq = (t & 7)*4;
      float4 v = *(const float4*)(DPm + ((size_t)(bh*NN) + i0 + r)*NN + j0 + jq);
      *(float4*)&dps[r][jq] = v;
    }
    if (!UNIF) {
      int mm = t >> 5, jj = t & 31;
      const float* src = Pi + ((size_t)(bh*8+mm))*SLAB + (size_t)(j0+jj)*16;
      float4 v0 = *(const float4*)(src);
      float4 v1 = *(const float4*)(src+4);
      float4 v2 = *(const float4*)(src+8);
      float4 v3 = *(const float4*)(src+12);
      *(float4*)&pjs[mm][jj][0]  = v0;
      *(float4*)&pjs[mm][jj][4]  = v1;
      *(float4*)&pjs[mm][jj][8]  = v2;
      *(float4*)&pjs[mm][jj][12] = v3;
    }
    __syncthreads();
    if (UNIF) {
      #pragma unroll 8
      for (int jj = 0; jj < 32; jj++) {
        float dp = dps[li][jj];
        rsum += dp; t1a += dp*dp;
      }
    } else {
      #pragma unroll 4
      for (int jj = 0; jj < 32; jj++) {
        float dp = dps[li][jj];
        t1 += dp*dp*mjs[m][j0+jj];
        float4 p0 = *(const float4*)&pjs[m][jj][0];
        float4 p1 = *(const float4*)&pjs[m][jj][4];
        float4 p2 = *(const float4*)&pjs[m][jj][8];
        float4 p3 = *(const float4*)&pjs[m][jj][12];
        w[0]  += dp*p0.x; w[1]  += dp*p0.y; w[2]  += dp*p0.z; w[3]  += dp*p0.w;
        w[4]  += dp*p1.x; w[5]  += dp*p1.y; w[6]  += dp*p1.z; w[7]  += dp*p1.w;
        w[8]  += dp*p2.x; w[9]  += dp*p2.y; w[10] += dp*p2.z; w[11] += dp*p2.w;
        w[12] += dp*p3.x; w[13] += dp*p3.y; w[14] += dp*p3.z; w[15] += dp*p3.w;
      }
    }
    __syncthreads();
  }
  if (UNIF) {
    t1 = t1a * (1.f/512.f);
    float wc = rsum * (1.f/8192.f);
    #pragma unroll
    for (int k = 0; k < 16; k++) w[k] = wc;
  }
  int bhm = bh*8 + m;
  float cb[16];
  #pragma unroll
  for (int k = 0; k < 16; k++) {
    float cr2 = 0.f;
    #pragma unroll
    for (int l = 0; l < 16; l++) cr2 += w[l]*dgs[m][k][l];
    cb[k] = fmaxf(t1 + t2s[m][k] - 2.f*cr2, 0.f);
  }
  float* Cb = C  + (size_t)bhm*SLAB + (size_t)(i0+li)*16;
  float* Kb = Km + (size_t)bhm*SLAB + (size_t)(i0+li)*16;
  #pragma unroll
  for (int q = 0; q < 4; q++) {
    float4 co; co.x = cb[q*4]; co.y = cb[q*4+1]; co.z = cb[q*4+2]; co.w = cb[q*4+3];
    *(float4*)(Cb + q*4) = co;
    float4 ko;
    ko.x = fmaxf(expf(-20.f*co.x), 1e-12f);
    ko.y = fmaxf(expf(-20.f*co.y), 1e-12f);
    ko.z = fmaxf(expf(-20.f*co.z), 1e-12f);
    ko.w = fmaxf(expf(-20.f*co.w), 1e-12f);
    *(float4*)(Kb + q*4) = ko;
  }
}

// ---------------- sinkhorn (10 iters fused) ----------------
__global__ void k_sinkhorn(const float* __restrict__ Km, float* __restrict__ Pi) {
  int bhm = blockIdx.x;
  const float* Kb = Km + (size_t)bhm*SLAB;
  __shared__ float KT[NK][NN+1];
  __shared__ float u[NN];
  __shared__ float v[NK];
  __shared__ float red[256][17];
  int t = threadIdx.x;
  for (int i = t; i < SLAB; i += 256) KT[i & 15][i >> 4] = Kb[i];
  if (t < NK) v[t] = 1.f/16.f;
  __syncthreads();
  for (int it = 0; it < 10; ++it) {
    #pragma unroll
    for (int i = 0; i < 2; i++) {
      int n = t + i*256;
      float s = 0.f;
      #pragma unroll
      for (int k = 0; k < NK; k++) s += KT[k][n]*v[k];
      u[n] = (1.f/512.f)/(s + 1e-6f);
    }
    __syncthreads();
    float accl[NK];
    #pragma unroll
    for (int k = 0; k < NK; k++) accl[k] = 0.f;
    #pragma unroll
    for (int i = 0; i < 2; i++) {
      int n = t + i*256; float un = u[n];
      #pragma unroll
      for (int k = 0; k < NK; k++) accl[k] += KT[k][n]*un;
    }
    #pragma unroll
    for (int k = 0; k < NK; k++) red[t][k] = accl[k];
    __syncthreads();
    for (int s = 128; s > 0; s >>= 1) {
      if (t < s) { for (int k = 0; k < NK; k++) red[t][k] += red[t+s][k]; }
      __syncthreads();
    }
    if (t < NK) v[t] = (1.f/16.f)/(red[0][t] + 1e-6f);
    __syncthreads();
  }
  float* Pib = Pi + (size_t)bhm*SLAB;
  for (int i = t; i < SLAB; i += 256) {
    int n = i >> 4, k = i & 15;
    Pib[i] = u[n]*KT[k][n]*v[k];
  }
}

// ---------------- gw_val ----------------
__global__ void k_gwval(const float* __restrict__ C, const float* __restrict__ Pi,
                        float* __restrict__ gw) {
  int bhm = blockIdx.x; int t = threadIdx.x;
  __shared__ float red[256];
  const float* Cb = C + (size_t)bhm*SLAB;
  const float* Pb = Pi + (size_t)bhm*SLAB;
  float s = 0.f;
  for (int i = t; i < SLAB; i += 256) s += Cb[i]*Pb[i];
  red[t] = s; __syncthreads();
  for (int q = 128; q > 0; q >>= 1) { if (t < q) red[t] += red[t+q]; __syncthreads(); }
  if (t == 0) gw[bhm] = red[0];
}

// ---------------- alpha ----------------
__global__ void k_alpha(const float* __restrict__ gw, float* __restrict__ alpha) {
  int t = threadIdx.x;
  float g = gw[t];
  float sc = expf(-(g*g));
  float s = sc;
  s += __shfl_xor(s, 1); s += __shfl_xor(s, 2); s += __shfl_xor(s, 4);
  alpha[t] = sc / fmaxf(s, 1e-8f);
}

// ---------------- Estack/PiStack bf16 conversion ----------------
__global__ __launch_bounds__(256) void k_estack(const float* __restrict__ Pi, const float* __restrict__ G,
                        const float* __restrict__ alpha,
                        unsigned short* __restrict__ Est, unsigned short* __restrict__ Pis) {
  int blk = blockIdx.x;      // 512: bh*8+m
  int m = blk & 7, bh = blk >> 3;
  __shared__ float Gs[16][16];
  int t = threadIdx.x;
  Gs[t >> 4][t & 15] = G[m*256 + t];
  float al = alpha[blk];
  __syncthreads();
  const float* Pib = Pi + (size_t)blk*SLAB;
  for (int r = t; r < NN; r += 256) {
    float p[16];
    #pragma unroll
    for (int q = 0; q < 4; q++) {
      float4 v = *(const float4*)(Pib + r*16 + q*4);
      p[q*4+0] = v.x; p[q*4+1] = v.y; p[q*4+2] = v.z; p[q*4+3] = v.w;
    }
    u16x8 e0, e1, p0, p1;
    #pragma unroll
    for (int l = 0; l < 16; l++) {
      float e = 0.f;
      #pragma unroll
      for (int k = 0; k < 16; k++) e += p[k]*Gs[k][l];
      unsigned short eb = f2bf(al*e);
      unsigned short pb = f2bf(p[l]);
      if (l < 8) { e0[l] = eb; p0[l] = pb; } else { e1[l-8] = eb; p1[l-8] = pb; }
    }
    size_t off = ((size_t)bh*NN + r)*128 + m*16;
    *(u16x8*)(Est + off)     = e0;
    *(u16x8*)(Est + off + 8) = e1;
    *(u16x8*)(Pis + off)     = p0;
    *(u16x8*)(Pis + off + 8) = p1;
  }
}

// ---------------- Q GEMM (MFMA bf16) + fused normalize + log ----------------
__global__ __launch_bounds__(256) void k_qgemm(const unsigned short* __restrict__ Est,
                       const unsigned short* __restrict__ Pis, float* __restrict__ out) {
  // XCD-aware swizzle: grid 1024, 8 XCDs -> contiguous 128-block chunks per XCD
  int bid = blockIdx.x;
  int blk = (bid & 7)*128 + (bid >> 3);
  int strip = blk & 15, bh = blk >> 4;
  int i0 = strip*32;
  __shared__ unsigned short As[32*128];   // 8 KB, XOR-swizzled rows
  __shared__ unsigned short Bs[128*128];  // 32 KB, XOR-swizzled rows
  __shared__ float rsum[4][32];
  int t = threadIdx.x;
  int w = t >> 6, lane = t & 63;
  const unsigned short* Ab = Est + ((size_t)bh*NN + i0)*128;
  #pragma unroll
  for (int q = 0; q < 2; q++) {
    int idx = q*256 + t;            // 512 16B-chunks
    int r = idx >> 4, sg = idx & 15;
    float4 v = *(const float4*)(Ab + r*128 + sg*8);
    *(float4*)&As[r*128 + (sg ^ (r & 7))*8] = v;
  }
  f32x4 acc[4][2][2] = {};
  const unsigned short* Bb = Pis + (size_t)bh*NN*128;
  for (int c = 0; c < 4; c++) {
    __syncthreads();
    #pragma unroll
    for (int q = 0; q < 8; q++) {
      int idx = q*256 + t;          // 2048 16B-chunks
      int r = idx >> 4, sg = idx & 15;
      float4 v = *(const float4*)(Bb + (size_t)(c*128 + r)*128 + sg*8);
      *(float4*)&Bs[r*128 + (sg ^ (r & 7))*8] = v;
    }
    __syncthreads();
    int col0 = w*32;
    #pragma unroll
    for (int ks = 0; ks < 4; ks++) {
      int slot = (ks*4 + (lane >> 4)) ^ (lane & 7);
      int la = lane & 15;
      bf16x8 a0 = *(bf16x8*)&As[la*128 + slot*8];
      bf16x8 a1 = *(bf16x8*)&As[(la+16)*128 + slot*8];
      bf16x8 b0 = *(bf16x8*)&Bs[(col0+la)*128 + slot*8];
      bf16x8 b1 = *(bf16x8*)&Bs[(col0+la+16)*128 + slot*8];
      acc[c][0][0] = __builtin_amdgcn_mfma_f32_16x16x32_bf16(a0, b0, acc[c][0][0], 0, 0, 0);
      acc[c][1][0] = __builtin_amdgcn_mfma_f32_16x16x32_bf16(a1, b0, acc[c][1][0], 0, 0, 0);
      acc[c][0][1] = __builtin_amdgcn_mfma_f32_16x16x32_bf16(a0, b1, acc[c][0][1], 0, 0, 0);
      acc[c][1][1] = __builtin_amdgcn_mfma_f32_16x16x32_bf16(a1, b1, acc[c][1][1], 0, 0, 0);
    }
  }
  // clipped row sums: C/D layout col=lane&15, row=(lane>>4)*4+reg
  float part[2][4];
  #pragma unroll
  for (int mt = 0; mt < 2; mt++) {
    #pragma unroll
    for (int rg = 0; rg < 4; rg++) {
      float s = 0.f;
      #pragma unroll
      for (int c = 0; c < 4; c++) {
        #pragma unroll
        for (int nt = 0; nt < 2; nt++) s += fmaxf(acc[c][mt][nt][rg], 1e-8f);
      }
      s += __shfl_xor(s, 1); s += __shfl_xor(s, 2);
      s += __shfl_xor(s, 4); s += __shfl_xor(s, 8);
      part[mt][rg] = s;
    }
  }
  if ((lane & 15) == 0) {
    int rgrp = lane >> 4;
    #pragma unroll
    for (int mt = 0; mt < 2; mt++)
      #pragma unroll
      for (int rg = 0; rg < 4; rg++)
        rsum[w][mt*16 + rgrp*4 + rg] = part[mt][rg];
  }
  __syncthreads();
  float invr[2][4];
  #pragma unroll
  for (int mt = 0; mt < 2; mt++) {
    #pragma unroll
    for (int rg = 0; rg < 4; rg++) {
      int row = mt*16 + (lane >> 4)*4 + rg;
      invr[mt][rg] = 1.f / (rsum[0][row] + rsum[1][row] + rsum[2][row] + rsum[3][row]);
    }
  }
  float* Qb = out + (size_t)QOFF + ((size_t)bh*NN + i0)*NN;
  float* Lb = out + ((size_t)bh*NN + i0)*NN;
  #pragma unroll
  for (int c = 0; c < 4; c++) {
    #pragma unroll
    for (int mt = 0; mt < 2; mt++) {
      #pragma unroll
      for (int nt = 0; nt < 2; nt++) {
        #pragma unroll
        for (int rg = 0; rg < 4; rg++) {
          int row = mt*16 + (lane >> 4)*4 + rg;
          int col = c*128 + w*32 + nt*16 + (lane & 15);
          float v = fmaxf(acc[c][mt][nt][rg], 1e-8f)*invr[mt][rg];
          Qb[(size_t)row*NN + col] = v;
          Lb[(size_t)row*NN + col] = __logf(v);
        }
      }
    }
  }
}

// ---------------- slot usage ----------------
__global__ __launch_bounds__(256) void k_usage(const float* __restrict__ z, const float* __restrict__ Wp,
                        const float* __restrict__ bp, float* __restrict__ partial) {
  __shared__ float wps[256][9];
  __shared__ float red[256][8];
  int t = threadIdx.x;
  {
    float4 a = *(const float4*)(Wp + t*8);
    float4 b = *(const float4*)(Wp + t*8 + 4);
    wps[t][0]=a.x; wps[t][1]=a.y; wps[t][2]=a.z; wps[t][3]=a.w;
    wps[t][4]=b.x; wps[t][5]=b.y; wps[t][6]=b.z; wps[t][7]=b.w;
  }
  __syncthreads();
  int row = blockIdx.x*256 + t;
  const float* zr = z + (size_t)row*ND;
  float acc[8] = {};
  for (int d0 = 0; d0 < ND; d0 += 4) {
    float4 v = *(const float4*)(zr + d0);
    #pragma unroll
    for (int m = 0; m < 8; m++) {
      acc[m] += v.x*wps[d0][m] + v.y*wps[d0+1][m] + v.z*wps[d0+2][m] + v.w*wps[d0+3][m];
    }
  }
  float mx = -1e30f;
  #pragma unroll
  for (int m = 0; m < 8; m++) { acc[m] += bp[m]; mx = fmaxf(mx, acc[m]); }
  float s = 0.f;
  #pragma unroll
  for (int m = 0; m < 8; m++) { acc[m] = expf(acc[m]-mx); s += acc[m]; }
  float inv = 1.f/s;
  #pragma unroll
  for (int m = 0; m < 8; m++) red[t][m] = acc[m]*inv;
  __syncthreads();
  for (int q = 128; q > 0; q >>= 1) {
    if (t < q) { for (int m = 0; m < 8; m++) red[t][m] += red[t+q][m]; }
    __syncthreads();
  }
  if (t < 8) partial[blockIdx.x*8 + t] = red[0][t];
}

// ---------------- final scalar ----------------
__global__ void k_final(const float* __restrict__ greg, const float* __restrict__ partial,
                        float* __restrict__ out) {
  if (threadIdx.x == 0) {
    float us[8] = {};
    for (int b = 0; b < 16; b++)
      for (int m = 0; m < 8; m++) us[m] += partial[b*8 + m];
    float kl = 0.f;
    for (int m = 0; m < 8; m++) {
      float u = us[m] / (float)BN;
      kl += u*logf(fmaxf(u, 1e-8f)*(float)NM);
    }
    out[33554432] = greg[0] + 0.01f*kl;
  }
}

extern "C" void kernel_launch(void* const* d_in, const int* in_sizes, int n_in,
                              void* d_out, int out_size, void* d_ws, size_t ws_size,
                              hipStream_t stream) {
  const float* xd = (const float*)d_in[0];
  const float* xn = (const float*)d_in[1];
  const float* W1 = (const float*)d_in[2];
  const float* b1 = (const float*)d_in[3];
  const float* W2 = (const float*)d_in[4];
  const float* b2 = (const float*)d_in[5];
  const float* Wp = (const float*)d_in[6];
  const float* bp = (const float*)d_in[7];
  const float* Up = (const float*)d_in[8];
  float* out = (float*)d_out;
  float* ws  = (float*)d_ws;

  float* z     = ws + 0;
  float* hid   = ws + 1048576;
  float* zh    = ws + 2097152;
  float* Pi    = ws + 3145728;    // 4,194,304 floats
  float* C     = ws + 7340032;    // 4,194,304 floats
  float* Km    = ws + 11534336;   // 4,194,304 floats (reused for Est/Pis)
  float* massj = ws + 15728640;
  float* partial = ws + 15990784;
  float* massl = ws + 16252928;
  float* term2 = ws + 16261120;
  float* gw    = ws + 16269312;
  float* alpha = ws + 16269824;
  float* G     = ws + 16270336;
  float* DG    = ws + 16272384;
  float* greg  = ws + 16274432;

  // Km region is dead after the last sinkhorn; reuse for bf16 stacks (16 MB exactly)
  unsigned short* Est = (unsigned short*)(ws + 11534336);
  unsigned short* Pis = (unsigned short*)(ws + 11534336 + 2097152);

  float* P  = out;                  // scratch in bias region
  float* DP = out + QOFF;           // scratch in Q region

  k_mlp1<<<dim3(4, 64), 256, 0, stream>>>(xd, xn, W1, b1, hid);
  k_mlp2<<<dim3(4, 64), 256, 0, stream>>>(hid, W2, b2, z);
  k_zhnorm<<<4096, 256, 0, stream>>>(z, zh);
  k_affinity<<<1024, 256, 0, stream>>>(zh, P);
  k_dp<<<1024, 256, 0, stream>>>(P, DP);
  k_slots<<<1, 256, 0, stream>>>(Up, G, DG, greg);
  // outer iter 0: uniform Pi handled analytically (no fillpi/mass needed)
  k_term2u<<<32, 256, 0, stream>>>(DG, term2);
  k_cost<1><<<1024, 256, 0, stream>>>(DP, nullptr, DG, nullptr, term2, C, Km);
  k_sinkhorn<<<BHM, 256, 0, stream>>>(Km, Pi);
  for (int it = 1; it < 3; ++it) {
    k_mass<<<BHM, 256, 0, stream>>>(Pi, massj, massl);
    k_term2<<<32, 256, 0, stream>>>(DG, massl, term2);
    k_cost<0><<<1024, 256, 0, stream>>>(DP, Pi, DG, massj, term2, C, Km);
    k_sinkhorn<<<BHM, 256, 0, stream>>>(Km, Pi);
  }
  k_gwval<<<BHM, 256, 0, stream>>>(C, Pi, gw);
  k_alpha<<<1, 512, 0, stream>>>(gw, alpha);
  k_estack<<<512, 256, 0, stream>>>(Pi, G, alpha, Est, Pis);
  k_qgemm<<<1024, 256, 0, stream>>>(Est, Pis, out);
  k_usage<<<16, 256, 0, stream>>>(z, Wp, bp, partial);
  k_final<<<1, 64, 0, stream>>>(greg, partial, out);
}

// Round 4
// 545.534 us; speedup vs baseline: 4.6968x; 1.4142x over previous
//
#include <hip/hip_runtime.h>
#include <cstdint>
#include <cstddef>

#define NB 8
#define NN 512
#define ND 256
#define NH 8
#define NM 8
#define NK 16
#define NR 8
#define NDH 32
#define BN (NB*NN)           // 4096 rows
#define BH (NB*NH)           // 64
#define BHN (BH*NN)          // 32768
#define BHM (BH*NM)          // 512
#define QOFF 16777216        // B*H*N*N

typedef __attribute__((ext_vector_type(8))) short bf16x8;
typedef __attribute__((ext_vector_type(8))) unsigned short u16x8;
typedef __attribute__((ext_vector_type(4))) float f32x4;

__device__ inline unsigned short f2bf(float x) {
  union { float f; unsigned u; } c; c.f = x;
  unsigned r = c.u + 0x7FFFu + ((c.u >> 16) & 1u);
  return (unsigned short)(r >> 16);
}
__device__ inline float bf2f(unsigned short x) {
  union { unsigned u; float f; } c; c.u = ((unsigned)x) << 16; return c.f;
}

// ---------------- MLP: 64x64 tile, 4x4 per thread ----------------
__global__ __launch_bounds__(256) void k_mlp1(const float* __restrict__ xd, const float* __restrict__ xn,
                       const float* __restrict__ W1, const float* __restrict__ b1,
                       float* __restrict__ hid) {
  __shared__ float As[16][68];   // [k][i]
  __shared__ float Bs[16][68];   // [k][j]
  int t = threadIdx.x;
  int col0 = blockIdx.x * 64;
  int row0 = blockIdx.y * 64;
  int ar = t >> 2, ak = (t & 3) * 4;
  int bk = t >> 4, bc = (t & 15) * 4;
  int ty = t >> 4, tx = t & 15;
  float acc[4][4] = {};
  for (int k0 = 0; k0 < 2*ND; k0 += 16) {
    int gk = k0 + ak;
    const float* src = (gk < ND) ? (xd + (size_t)(row0+ar)*ND + gk)
                                 : (xn + (size_t)(row0+ar)*ND + (gk-ND));
    float4 av = *(const float4*)src;
    As[ak+0][ar] = av.x; As[ak+1][ar] = av.y; As[ak+2][ar] = av.z; As[ak+3][ar] = av.w;
    float4 bv = *(const float4*)(W1 + (size_t)(k0+bk)*ND + col0 + bc);
    *(float4*)&Bs[bk][bc] = bv;
    __syncthreads();
    #pragma unroll
    for (int kk = 0; kk < 16; kk++) {
      float4 a = *(const float4*)&As[kk][ty*4];
      float4 b = *(const float4*)&Bs[kk][tx*4];
      acc[0][0] += a.x*b.x; acc[0][1] += a.x*b.y; acc[0][2] += a.x*b.z; acc[0][3] += a.x*b.w;
      acc[1][0] += a.y*b.x; acc[1][1] += a.y*b.y; acc[1][2] += a.y*b.z; acc[1][3] += a.y*b.w;
      acc[2][0] += a.z*b.x; acc[2][1] += a.z*b.y; acc[2][2] += a.z*b.z; acc[2][3] += a.z*b.w;
      acc[3][0] += a.w*b.x; acc[3][1] += a.w*b.y; acc[3][2] += a.w*b.z; acc[3][3] += a.w*b.w;
    }
    __syncthreads();
  }
  float4 bb = *(const float4*)(b1 + col0 + tx*4);
  #pragma unroll
  for (int a = 0; a < 4; a++) {
    float4 o;
    o.x = fmaxf(acc[a][0] + bb.x, 0.f);
    o.y = fmaxf(acc[a][1] + bb.y, 0.f);
    o.z = fmaxf(acc[a][2] + bb.z, 0.f);
    o.w = fmaxf(acc[a][3] + bb.w, 0.f);
    *(float4*)(hid + (size_t)(row0+ty*4+a)*ND + col0 + tx*4) = o;
  }
}

__global__ __launch_bounds__(256) void k_mlp2(const float* __restrict__ hidp,
                       const float* __restrict__ W2, const float* __restrict__ b2,
                       float* __restrict__ z) {
  __shared__ float As[16][68];
  __shared__ float Bs[16][68];
  int t = threadIdx.x;
  int col0 = blockIdx.x * 64;
  int row0 = blockIdx.y * 64;
  int ar = t >> 2, ak = (t & 3) * 4;
  int bk = t >> 4, bc = (t & 15) * 4;
  int ty = t >> 4, tx = t & 15;
  float acc[4][4] = {};
  for (int k0 = 0; k0 < ND; k0 += 16) {
    float4 av = *(const float4*)(hidp + (size_t)(row0+ar)*ND + k0 + ak);
    As[ak+0][ar] = av.x; As[ak+1][ar] = av.y; As[ak+2][ar] = av.z; As[ak+3][ar] = av.w;
    float4 bv = *(const float4*)(W2 + (size_t)(k0+bk)*ND + col0 + bc);
    *(float4*)&Bs[bk][bc] = bv;
    __syncthreads();
    #pragma unroll
    for (int kk = 0; kk < 16; kk++) {
      float4 a = *(const float4*)&As[kk][ty*4];
      float4 b = *(const float4*)&Bs[kk][tx*4];
      acc[0][0] += a.x*b.x; acc[0][1] += a.x*b.y; acc[0][2] += a.x*b.z; acc[0][3] += a.x*b.w;
      acc[1][0] += a.y*b.x; acc[1][1] += a.y*b.y; acc[1][2] += a.y*b.z; acc[1][3] += a.y*b.w;
      acc[2][0] += a.z*b.x; acc[2][1] += a.z*b.y; acc[2][2] += a.z*b.z; acc[2][3] += a.z*b.w;
      acc[3][0] += a.w*b.x; acc[3][1] += a.w*b.y; acc[3][2] += a.w*b.z; acc[3][3] += a.w*b.w;
    }
    __syncthreads();
  }
  float4 bb = *(const float4*)(b2 + col0 + tx*4);
  #pragma unroll
  for (int a = 0; a < 4; a++) {
    float4 o;
    o.x = acc[a][0] + bb.x; o.y = acc[a][1] + bb.y;
    o.z = acc[a][2] + bb.z; o.w = acc[a][3] + bb.w;
    *(float4*)(z + (size_t)(row0+ty*4+a)*ND + col0 + tx*4) = o;
  }
}

// ---------------- zh normalize ----------------
__global__ void k_zhnorm(const float* __restrict__ z, float* __restrict__ zh) {
  int idx = blockIdx.x*256 + threadIdx.x;
  int d = idx & 31;
  int n = (idx >> 5) & (NN-1);
  int h = (idx >> 14) & (NH-1);
  int b = idx >> 17;
  float v = z[(size_t)(b*NN + n)*ND + h*NDH + d];
  float ss = v*v;
  #pragma unroll
  for (int m = 1; m < 32; m <<= 1) ss += __shfl_xor(ss, m);
  zh[idx] = v / fmaxf(sqrtf(ss), 1e-8f);
}

// ---------------- affinity + softmax -> P ----------------
__global__ __launch_bounds__(256) void k_affinity(const float* __restrict__ zh, float* __restrict__ P) {
  int blk = blockIdx.x;               // 64 bh * 16 rowtiles
  int rt = blk & 15, bh = blk >> 4;
  int r0 = rt*32;
  const float* base = zh + (size_t)bh*NN*NDH;
  __shared__ float qs[32][33];
  __shared__ float ks[32][36];        // [d][s]
  int t = threadIdx.x;
  int sr = t >> 3, dq = (t & 7)*4;
  {
    float4 v = *(const float4*)(base + (size_t)(r0+sr)*NDH + dq);
    qs[sr][dq] = v.x; qs[sr][dq+1] = v.y; qs[sr][dq+2] = v.z; qs[sr][dq+3] = v.w;
  }
  int cr = t >> 3;
  int cq = t & 7;
  float acc[16][4];
  #pragma unroll
  for (int ti = 0; ti < 16; ti++) { acc[ti][0]=0; acc[ti][1]=0; acc[ti][2]=0; acc[ti][3]=0; }
  for (int ti = 0; ti < 16; ti++) {
    int s0 = ti*32;
    __syncthreads();
    {
      float4 v = *(const float4*)(base + (size_t)(s0+sr)*NDH + dq);
      ks[dq+0][sr] = v.x; ks[dq+1][sr] = v.y; ks[dq+2][sr] = v.z; ks[dq+3][sr] = v.w;
    }
    __syncthreads();
    #pragma unroll
    for (int d = 0; d < 32; d++) {
      float qv = qs[cr][d];
      float4 kv = *(const float4*)&ks[d][cq*4];
      acc[ti][0] += qv*kv.x; acc[ti][1] += qv*kv.y;
      acc[ti][2] += qv*kv.z; acc[ti][3] += qv*kv.w;
    }
  }
  int gr = r0 + cr;
  float mx = -1e30f;
  #pragma unroll
  for (int ti = 0; ti < 16; ti++) {
    #pragma unroll
    for (int j = 0; j < 4; j++) {
      int s = ti*32 + cq*4 + j;
      float v = (s == gr) ? -1e9f : acc[ti][j]*0.0625f;
      acc[ti][j] = v;
      mx = fmaxf(mx, v);
    }
  }
  mx = fmaxf(mx, __shfl_xor(mx, 1));
  mx = fmaxf(mx, __shfl_xor(mx, 2));
  mx = fmaxf(mx, __shfl_xor(mx, 4));
  float sum = 0.f;
  #pragma unroll
  for (int ti = 0; ti < 16; ti++) {
    #pragma unroll
    for (int j = 0; j < 4; j++) { float e = expf(acc[ti][j]-mx); acc[ti][j] = e; sum += e; }
  }
  sum += __shfl_xor(sum,1); sum += __shfl_xor(sum,2); sum += __shfl_xor(sum,4);
  float inv = 1.f/sum;
  float* prow = P + ((size_t)(bh*NN) + gr)*NN;
  #pragma unroll
  for (int ti = 0; ti < 16; ti++) {
    float4 o; o.x = acc[ti][0]*inv; o.y = acc[ti][1]*inv; o.z = acc[ti][2]*inv; o.w = acc[ti][3]*inv;
    *(float4*)(prow + ti*32 + cq*4) = o;
  }
}

// ---------------- DP: symmetrize + row-normalize -> bf16 ----------------
__global__ __launch_bounds__(256) void k_dp(const float* __restrict__ P, unsigned short* __restrict__ DPo) {
  int blk = blockIdx.x;               // 64*16
  int rt = blk & 15, bh = blk >> 4;
  int r0 = rt*32;
  const float* Pb = P + (size_t)bh*NN*NN;
  __shared__ float Bs[32][33];
  int t = threadIdx.x;
  int r = t >> 3, q4 = (t & 7)*4;
  float pn[16][4];
  float rowacc = 0.f;
  for (int ti = 0; ti < 16; ti++) {
    int s0 = ti*32;
    __syncthreads();
    {
      float4 v = *(const float4*)(Pb + (size_t)(s0+r)*NN + r0 + q4);
      Bs[r][q4] = v.x; Bs[r][q4+1] = v.y; Bs[r][q4+2] = v.z; Bs[r][q4+3] = v.w;
    }
    float4 a = *(const float4*)(Pb + (size_t)(r0+r)*NN + s0 + q4);
    __syncthreads();
    float p0 = fmaxf(0.5f*(a.x + Bs[q4+0][r]), 1e-8f);
    float p1 = fmaxf(0.5f*(a.y + Bs[q4+1][r]), 1e-8f);
    float p2 = fmaxf(0.5f*(a.z + Bs[q4+2][r]), 1e-8f);
    float p3 = fmaxf(0.5f*(a.w + Bs[q4+3][r]), 1e-8f);
    pn[ti][0]=p0; pn[ti][1]=p1; pn[ti][2]=p2; pn[ti][3]=p3;
    rowacc += p0+p1+p2+p3;
  }
  rowacc += __shfl_xor(rowacc,1); rowacc += __shfl_xor(rowacc,2); rowacc += __shfl_xor(rowacc,4);
  float inv = 1.f / fmaxf(rowacc, 1e-8f);
  unsigned short* drow = DPo + ((size_t)(bh*NN) + r0 + r)*NN;
  #pragma unroll
  for (int ti = 0; ti < 16; ti++) {
    float o0 = fmaxf(1.f - pn[ti][0]*inv, 0.f);
    float o1 = fmaxf(1.f - pn[ti][1]*inv, 0.f);
    float o2 = fmaxf(1.f - pn[ti][2]*inv, 0.f);
    float o3 = fmaxf(1.f - pn[ti][3]*inv, 0.f);
    uint2 pk;
    pk.x = (unsigned)f2bf(o0) | ((unsigned)f2bf(o1) << 16);
    pk.y = (unsigned)f2bf(o2) | ((unsigned)f2bf(o3) << 16);
    *(uint2*)(drow + ti*32 + q4) = pk;
  }
}

// ---------------- slot graphs: G, g_reg, DG ----------------
__global__ void k_slots(const float* __restrict__ Up, float* __restrict__ G,
                        float* __restrict__ DG, float* __restrict__ greg) {
  __shared__ float U[NM*NK*NR];
  __shared__ float Gs[NM*NK*NK];
  __shared__ float rs[NM*NK];
  __shared__ float vn[NM];
  __shared__ float gram[NM*NM];
  int t = threadIdx.x;
  for (int i = t; i < NM*NK*NR; i += 256) {
    float x = Up[i];
    U[i] = fmaxf(x, 0.f) + log1pf(expf(-fabsf(x)));
  }
  __syncthreads();
  for (int i = t; i < NM*NK*NK; i += 256) {
    int m = i >> 8, k = (i >> 4) & 15, j = i & 15;
    float acc = 0.f;
    #pragma unroll
    for (int r = 0; r < NR; r++) acc += U[(m*NK+k)*NR + r]*U[(m*NK+j)*NR + r];
    Gs[i] = acc;
  }
  __syncthreads();
  for (int i = t; i < NM*NK; i += 256) {
    float s = 0.f;
    #pragma unroll
    for (int j = 0; j < NK; j++) s += Gs[i*NK + j];
    rs[i] = fmaxf(s, 1e-8f);
  }
  __syncthreads();
  for (int i = t; i < NM*NK*NK; i += 256) { Gs[i] /= rs[i >> 4]; G[i] = Gs[i]; }
  __syncthreads();
  for (int i = t; i < NM; i += 256) {
    float s = 0.f;
    for (int j = 0; j < NK*NK; j++) { float g = Gs[i*NK*NK + j]; s += g*g; }
    vn[i] = fmaxf(sqrtf(s), 1e-8f);
  }
  __syncthreads();
  for (int i = t; i < NM*NM; i += 256) {
    int a = i >> 3, b = i & 7;
    float s = 0.f;
    for (int j = 0; j < NK*NK; j++) s += Gs[a*NK*NK + j]*Gs[b*NK*NK + j];
    gram[i] = s / (vn[a]*vn[b]);
  }
  __syncthreads();
  if (t == 0) {
    float s = 0.f;
    for (int i = 0; i < NM*NM; i++) if ((i >> 3) != (i & 7)) s += gram[i];
    greg[0] = 0.1f * s / (float)(NM*(NM-1));
  }
  for (int i = t; i < NM*NK*NK; i += 256) {
    int m = i >> 8, k = (i >> 4) & 15, j = i & 15;
    float dk = fmaxf(Gs[m*NK*NK + k*NK + k], 1e-8f);
    float dj = fmaxf(Gs[m*NK*NK + j*NK + j], 1e-8f);
    float den = fmaxf(sqrtf(dk*dj), 1e-8f);
    float c = fminf(fmaxf(Gs[i]/den, -1.f), 1.f);
    float d = fmaxf(1.f - c, 0.f);
    if (k == j) d = 0.f;
    DG[i] = d;
  }
}

// ---------------- fused GW: 3 outer iters, cost(MFMA)+sinkhorn+mass in LDS ----------------
#define DSTR 40     // DP tile row stride (bf16)
#define KSTR 513    // KT row stride (f32)
#define PSTR 520    // PiT row stride (bf16)
__global__ __launch_bounds__(512) void k_gw(
    const unsigned short* __restrict__ DPb,   // [64][512][512] bf16
    const float* __restrict__ Gm,             // [8][16][16]
    const float* __restrict__ DGm,            // [8][16][16]
    unsigned short* __restrict__ PiGs,        // [64][512][8][16] bf16
    unsigned short* __restrict__ Pis,         // same layout
    float* __restrict__ gwv) {                // [512]
  int blk = blockIdx.x;
  int xcd = blk & 7, seq = blk >> 3;
  int bh = xcd*8 + (seq >> 3);                // all 8 m of a bh on one XCD -> L2 reuse
  int m  = seq & 7;
  __shared__ unsigned short DPs[512*DSTR];    // 40 KB
  __shared__ float KT[16*KSTR];               // 32.8 KB
  __shared__ unsigned short PiT[16*PSTR];     // 16.6 KB
  __shared__ float u[512], mj[512], t1s[512];
  __shared__ float vv[16], ml[16], t2s[16], dgrow[16];
  __shared__ float Gs[16][17], DGs[16][17];
  __shared__ float sred[8][16];
  int t = threadIdx.x;
  int lane = t & 63, w = t >> 6;
  int il = lane & 15, q = lane >> 4;
  if (t < 256) { Gs[t>>4][t&15] = Gm[m*256 + t]; DGs[t>>4][t&15] = DGm[m*256 + t]; }
  __syncthreads();
  if (t < 16) {
    float s = 0.f;
    #pragma unroll
    for (int l = 0; l < 16; l++) s += DGs[t][l];
    dgrow[t] = s;
  }
  const unsigned short* DPbase = DPb + (size_t)bh*NN*NN;
  float creg[4][4];
  float gwp = 0.f;
  for (int it = 0; it < 3; ++it) {
    // ---- t2 from massl (uniform at it 0) ----
    if (t < 16) {
      float s = 0.f;
      #pragma unroll
      for (int l = 0; l < 16; l++) { float d = DGs[t][l]; s += d*d*((it == 0) ? (1.f/16.f) : ml[l]); }
      t2s[t] = s;
    }
    __syncthreads();
    // ---- stream DP tiles: MFMA cross + t1 ----
    f32x4 acc0 = {0,0,0,0}, acc1 = {0,0,0,0}, acc2 = {0,0,0,0}, acc3 = {0,0,0,0};
    float t1v = 0.f, rsv = 0.f;
    float4 cur0, cur1, cur2, cur3;
    {
      int id;
      id = t;        cur0 = *(const float4*)(DPbase + (size_t)(id>>2)*NN + (id&3)*8);
      id = 512 + t;  cur1 = *(const float4*)(DPbase + (size_t)(id>>2)*NN + (id&3)*8);
      id = 1024 + t; cur2 = *(const float4*)(DPbase + (size_t)(id>>2)*NN + (id&3)*8);
      id = 1536 + t; cur3 = *(const float4*)(DPbase + (size_t)(id>>2)*NN + (id&3)*8);
    }
    for (int jt = 0; jt < 16; jt++) {
      {
        int id;
        id = t;        *(float4*)&DPs[(id>>2)*DSTR + (id&3)*8] = cur0;
        id = 512 + t;  *(float4*)&DPs[(id>>2)*DSTR + (id&3)*8] = cur1;
        id = 1024 + t; *(float4*)&DPs[(id>>2)*DSTR + (id&3)*8] = cur2;
        id = 1536 + t; *(float4*)&DPs[(id>>2)*DSTR + (id&3)*8] = cur3;
      }
      __syncthreads();
      if (jt < 15) {   // prefetch next tile (hidden under compute)
        int j2 = (jt+1)*32; int id;
        id = t;        cur0 = *(const float4*)(DPbase + (size_t)(id>>2)*NN + j2 + (id&3)*8);
        id = 512 + t;  cur1 = *(const float4*)(DPbase + (size_t)(id>>2)*NN + j2 + (id&3)*8);
        id = 1024 + t; cur2 = *(const float4*)(DPbase + (size_t)(id>>2)*NN + j2 + (id&3)*8);
        id = 1536 + t; cur3 = *(const float4*)(DPbase + (size_t)(id>>2)*NN + j2 + (id&3)*8);
      }
      if (it == 0) {
        #pragma unroll
        for (int seg = 0; seg < 4; seg++) {
          u16x8 dv = *(const u16x8*)&DPs[t*DSTR + seg*8];
          #pragma unroll
          for (int e = 0; e < 8; e++) { float dp = bf2f(dv[e]); rsv += dp; t1v += dp*dp; }
        }
      } else {
        bf16x8 af = *(const bf16x8*)&PiT[il*PSTR + jt*32 + q*8];
        bf16x8 b0 = *(const bf16x8*)&DPs[(w*64 +  0 + il)*DSTR + q*8];
        bf16x8 b1 = *(const bf16x8*)&DPs[(w*64 + 16 + il)*DSTR + q*8];
        bf16x8 b2 = *(const bf16x8*)&DPs[(w*64 + 32 + il)*DSTR + q*8];
        bf16x8 b3 = *(const bf16x8*)&DPs[(w*64 + 48 + il)*DSTR + q*8];
        acc0 = __builtin_amdgcn_mfma_f32_16x16x32_bf16(af, b0, acc0, 0, 0, 0);
        acc1 = __builtin_amdgcn_mfma_f32_16x16x32_bf16(af, b1, acc1, 0, 0, 0);
        acc2 = __builtin_amdgcn_mfma_f32_16x16x32_bf16(af, b2, acc2, 0, 0, 0);
        acc3 = __builtin_amdgcn_mfma_f32_16x16x32_bf16(af, b3, acc3, 0, 0, 0);
        #pragma unroll
        for (int seg = 0; seg < 4; seg++) {
          u16x8 dv = *(const u16x8*)&DPs[t*DSTR + seg*8];
          #pragma unroll
          for (int e = 0; e < 8; e++) { float dp = bf2f(dv[e]); t1v += dp*dp*mj[jt*32 + seg*8 + e]; }
        }
      }
      __syncthreads();
    }
    // ---- epilogue: C -> KT (exp) ----
    if (it == 0) {
      float t1 = t1v*(1.f/512.f);
      float wc = rsv*(1.f/8192.f);
      #pragma unroll
      for (int k = 0; k < 16; k++) {
        float c = fmaxf(t1 + t2s[k] - 2.f*wc*dgrow[k], 0.f);
        KT[k*KSTR + t] = fmaxf(__expf(-20.f*c), 1e-12f);
      }
    } else {
      t1s[t] = t1v;
      __syncthreads();
      #pragma unroll
      for (int tt = 0; tt < 4; tt++) {
        f32x4 av = (tt==0)?acc0:((tt==1)?acc1:((tt==2)?acc2:acc3));
        float pc[16];
        #pragma unroll
        for (int k = 0; k < 16; k++) {
          pc[k] = av[0]*DGs[k][q*4+0] + av[1]*DGs[k][q*4+1]
                + av[2]*DGs[k][q*4+2] + av[3]*DGs[k][q*4+3];
        }
        #pragma unroll
        for (int k = 0; k < 16; k++) { pc[k] += __shfl_xor(pc[k], 16); pc[k] += __shfl_xor(pc[k], 32); }
        int i = w*64 + tt*16 + il;
        float t1i = t1s[i];
        #pragma unroll
        for (int kk = 0; kk < 4; kk++) {
          int k = q*4 + kk;
          float c = fmaxf(t1i + t2s[k] - 2.f*pc[k], 0.f);
          creg[tt][kk] = c;
          KT[k*KSTR + i] = fmaxf(__expf(-20.f*c), 1e-12f);
        }
      }
    }
    __syncthreads();
    // ---- sinkhorn: 10 iters ----
    if (t < 16) vv[t] = 1.f/16.f;
    __syncthreads();
    for (int si = 0; si < 10; si++) {
      float s = 0.f;
      #pragma unroll
      for (int k = 0; k < 16; k++) s += KT[k*KSTR + t]*vv[k];
      u[t] = (1.f/512.f)/(s + 1e-6f);
      __syncthreads();
      {
        int g = t >> 4, k = t & 15;
        float p = 0.f;
        #pragma unroll
        for (int jj = 0; jj < 16; jj++) { int j = g*16 + jj; p += KT[k*KSTR + j]*u[j]; }
        p += __shfl_xor(p, 16); p += __shfl_xor(p, 32);
        if (lane < 16) sred[w][lane] = p;
      }
      __syncthreads();
      if (t < 16) {
        float S = 0.f;
        #pragma unroll
        for (int w2 = 0; w2 < 8; w2++) S += sred[w2][t];
        vv[t] = (1.f/16.f)/(S + 1e-6f);
      }
      __syncthreads();
    }
    if (it < 2) {
      // massj for next iter
      {
        float s = 0.f;
        #pragma unroll
        for (int k = 0; k < 16; k++) s += KT[k*KSTR + t]*vv[k];
        mj[t] = u[t]*s;
      }
      // massl partial
      {
        int g = t >> 4, k = t & 15;
        float p = 0.f;
        #pragma unroll
        for (int jj = 0; jj < 16; jj++) { int j = g*16 + jj; p += KT[k*KSTR + j]*u[j]; }
        p += __shfl_xor(p, 16); p += __shfl_xor(p, 32);
        if (lane < 16) sred[w][lane] = p;
      }
      __syncthreads();
      if (t < 16) {
        float S = 0.f;
        #pragma unroll
        for (int w2 = 0; w2 < 8; w2++) S += sred[w2][t];
        ml[t] = vv[t]*S;
      }
      // PiT (bf16) for next iter's MFMA
      {
        int g = t >> 4, k = t & 15;
        float vk = vv[k];
        #pragma unroll
        for (int qq = 0; qq < 8; qq++) {
          int j0 = g*16 + qq*2;
          float p0 = u[j0]*KT[k*KSTR + j0]*vk;
          float p1 = u[j0+1]*KT[k*KSTR + j0+1]*vk;
          unsigned pk = (unsigned)f2bf(p0) | ((unsigned)f2bf(p1) << 16);
          *(unsigned*)&PiT[k*PSTR + g*16 + qq*2] = pk;
        }
      }
      __syncthreads();
    } else {
      // ---- final: write Pi(bf16) + PiG(bf16) stacks; gw = sum(C*Pi) ----
      float pi[16];
      #pragma unroll
      for (int k = 0; k < 16; k++) pi[k] = u[t]*KT[k*KSTR + t]*vv[k];
      size_t ob = ((size_t)bh*NN + t)*128 + m*16;
      {
        uint4 w0, w1;
        w0.x = (unsigned)f2bf(pi[0])  | ((unsigned)f2bf(pi[1])  << 16);
        w0.y = (unsigned)f2bf(pi[2])  | ((unsigned)f2bf(pi[3])  << 16);
        w0.z = (unsigned)f2bf(pi[4])  | ((unsigned)f2bf(pi[5])  << 16);
        w0.w = (unsigned)f2bf(pi[6])  | ((unsigned)f2bf(pi[7])  << 16);
        w1.x = (unsigned)f2bf(pi[8])  | ((unsigned)f2bf(pi[9])  << 16);
        w1.y = (unsigned)f2bf(pi[10]) | ((unsigned)f2bf(pi[11]) << 16);
        w1.z = (unsigned)f2bf(pi[12]) | ((unsigned)f2bf(pi[13]) << 16);
        w1.w = (unsigned)f2bf(pi[14]) | ((unsigned)f2bf(pi[15]) << 16);
        *(uint4*)(Pis + ob) = w0;
        *(uint4*)(Pis + ob + 8) = w1;
      }
      float pig[16];
      #pragma unroll
      for (int l = 0; l < 16; l++) {
        float s = 0.f;
        #pragma unroll
        for (int k = 0; k < 16; k++) s += pi[k]*Gs[k][l];
        pig[l] = s;
      }
      {
        uint4 w0, w1;
        w0.x = (unsigned)f2bf(pig[0])  | ((unsigned)f2bf(pig[1])  << 16);
        w0.y = (unsigned)f2bf(pig[2])  | ((unsigned)f2bf(pig[3])  << 16);
        w0.z = (unsigned)f2bf(pig[4])  | ((unsigned)f2bf(pig[5])  << 16);
        w0.w = (unsigned)f2bf(pig[6])  | ((unsigned)f2bf(pig[7])  << 16);
        w1.x = (unsigned)f2bf(pig[8])  | ((unsigned)f2bf(pig[9])  << 16);
        w1.y = (unsigned)f2bf(pig[10]) | ((unsigned)f2bf(pig[11]) << 16);
        w1.z = (unsigned)f2bf(pig[12]) | ((unsigned)f2bf(pig[13]) << 16);
        w1.w = (unsigned)f2bf(pig[14]) | ((unsigned)f2bf(pig[15]) << 16);
        *(uint4*)(PiGs + ob) = w0;
        *(uint4*)(PiGs + ob + 8) = w1;
      }
      #pragma unroll
      for (int tt = 0; tt < 4; tt++) {
        int i = w*64 + tt*16 + il;
        #pragma unroll
        for (int kk = 0; kk < 4; kk++) {
          int k = q*4 + kk;
          gwp += creg[tt][kk]*(u[i]*KT[k*KSTR + i]*vv[k]);
        }
      }
      #pragma unroll
      for (int off = 1; off < 64; off <<= 1) gwp += __shfl_xor(gwp, off);
      if (lane == 0) sred[w][0] = gwp;
      __syncthreads();
      if (t == 0) {
        float S = 0.f;
        #pragma unroll
        for (int w2 = 0; w2 < 8; w2++) S += sred[w2][0];
        gwv[bh*8 + m] = S;
      }
    }
  }
}

// ---------------- alpha ----------------
__global__ void k_alpha(const float* __restrict__ gw, float* __restrict__ alpha) {
  int t = threadIdx.x;
  float g = gw[t];
  float sc = expf(-(g*g));
  float s = sc;
  s += __shfl_xor(s, 1); s += __shfl_xor(s, 2); s += __shfl_xor(s, 4);
  alpha[t] = sc / fmaxf(s, 1e-8f);
}

// ---------------- Est = alpha * PiG ----------------
__global__ __launch_bounds__(256) void k_estack2(const unsigned short* __restrict__ PiGs,
                        const float* __restrict__ alpha, unsigned short* __restrict__ Est) {
  int tid = blockIdx.x*256 + threadIdx.x;   // 262144 = BH*NN*NM
  int bh = tid >> 12, mm = tid & 7;
  float al = alpha[bh*8 + mm];
  const unsigned short* src = PiGs + (size_t)tid*16;
  unsigned short* dst = Est + (size_t)tid*16;
  u16x8 a = *(const u16x8*)src;
  u16x8 b = *(const u16x8*)(src + 8);
  u16x8 oa, ob2;
  #pragma unroll
  for (int e = 0; e < 8; e++) { oa[e] = f2bf(bf2f(a[e])*al); ob2[e] = f2bf(bf2f(b[e])*al); }
  *(u16x8*)dst = oa;
  *(u16x8*)(dst + 8) = ob2;
}

// ---------------- Q GEMM (MFMA bf16) + fused normalize + log ----------------
__global__ __launch_bounds__(256) void k_qgemm(const unsigned short* __restrict__ Est,
                       const unsigned short* __restrict__ Pis, float* __restrict__ out) {
  int bid = blockIdx.x;
  int blk = (bid & 7)*128 + (bid >> 3);
  int strip = blk & 15, bh = blk >> 4;
  int i0 = strip*32;
  __shared__ unsigned short As[32*128];   // 8 KB, XOR-swizzled rows
  __shared__ unsigned short Bs[128*128];  // 32 KB, XOR-swizzled rows
  __shared__ float rsum[4][32];
  int t = threadIdx.x;
  int w = t >> 6, lane = t & 63;
  const unsigned short* Ab = Est + ((size_t)bh*NN + i0)*128;
  #pragma unroll
  for (int q = 0; q < 2; q++) {
    int idx = q*256 + t;
    int r = idx >> 4, sg = idx & 15;
    float4 v = *(const float4*)(Ab + r*128 + sg*8);
    *(float4*)&As[r*128 + (sg ^ (r & 7))*8] = v;
  }
  f32x4 acc[4][2][2] = {};
  const unsigned short* Bb = Pis + (size_t)bh*NN*128;
  for (int c = 0; c < 4; c++) {
    __syncthreads();
    #pragma unroll
    for (int q = 0; q < 8; q++) {
      int idx = q*256 + t;
      int r = idx >> 4, sg = idx & 15;
      float4 v = *(const float4*)(Bb + (size_t)(c*128 + r)*128 + sg*8);
      *(float4*)&Bs[r*128 + (sg ^ (r & 7))*8] = v;
    }
    __syncthreads();
    int col0 = w*32;
    #pragma unroll
    for (int ks = 0; ks < 4; ks++) {
      int slot = (ks*4 + (lane >> 4)) ^ (lane & 7);
      int la = lane & 15;
      bf16x8 a0 = *(bf16x8*)&As[la*128 + slot*8];
      bf16x8 a1 = *(bf16x8*)&As[(la+16)*128 + slot*8];
      bf16x8 b0 = *(bf16x8*)&Bs[(col0+la)*128 + slot*8];
      bf16x8 b1 = *(bf16x8*)&Bs[(col0+la+16)*128 + slot*8];
      acc[c][0][0] = __builtin_amdgcn_mfma_f32_16x16x32_bf16(a0, b0, acc[c][0][0], 0, 0, 0);
      acc[c][1][0] = __builtin_amdgcn_mfma_f32_16x16x32_bf16(a1, b0, acc[c][1][0], 0, 0, 0);
      acc[c][0][1] = __builtin_amdgcn_mfma_f32_16x16x32_bf16(a0, b1, acc[c][0][1], 0, 0, 0);
      acc[c][1][1] = __builtin_amdgcn_mfma_f32_16x16x32_bf16(a1, b1, acc[c][1][1], 0, 0, 0);
    }
  }
  float part[2][4];
  #pragma unroll
  for (int mt = 0; mt < 2; mt++) {
    #pragma unroll
    for (int rg = 0; rg < 4; rg++) {
      float s = 0.f;
      #pragma unroll
      for (int c = 0; c < 4; c++) {
        #pragma unroll
        for (int nt = 0; nt < 2; nt++) s += fmaxf(acc[c][mt][nt][rg], 1e-8f);
      }
      s += __shfl_xor(s, 1); s += __shfl_xor(s, 2);
      s += __shfl_xor(s, 4); s += __shfl_xor(s, 8);
      part[mt][rg] = s;
    }
  }
  if ((lane & 15) == 0) {
    int rgrp = lane >> 4;
    #pragma unroll
    for (int mt = 0; mt < 2; mt++)
      #pragma unroll
      for (int rg = 0; rg < 4; rg++)
        rsum[w][mt*16 + rgrp*4 + rg] = part[mt][rg];
  }
  __syncthreads();
  float invr[2][4];
  #pragma unroll
  for (int mt = 0; mt < 2; mt++) {
    #pragma unroll
    for (int rg = 0; rg < 4; rg++) {
      int row = mt*16 + (lane >> 4)*4 + rg;
      invr[mt][rg] = 1.f / (rsum[0][row] + rsum[1][row] + rsum[2][row] + rsum[3][row]);
    }
  }
  float* Qb = out + (size_t)QOFF + ((size_t)bh*NN + i0)*NN;
  float* Lb = out + ((size_t)bh*NN + i0)*NN;
  #pragma unroll
  for (int c = 0; c < 4; c++) {
    #pragma unroll
    for (int mt = 0; mt < 2; mt++) {
      #pragma unroll
      for (int nt = 0; nt < 2; nt++) {
        #pragma unroll
        for (int rg = 0; rg < 4; rg++) {
          int row = mt*16 + (lane >> 4)*4 + rg;
          int col = c*128 + w*32 + nt*16 + (lane & 15);
          float v = fmaxf(acc[c][mt][nt][rg], 1e-8f)*invr[mt][rg];
          Qb[(size_t)row*NN + col] = v;
          Lb[(size_t)row*NN + col] = __logf(v);
        }
      }
    }
  }
}

// ---------------- slot usage ----------------
__global__ __launch_bounds__(256) void k_usage(const float* __restrict__ z, const float* __restrict__ Wp,
                        const float* __restrict__ bp, float* __restrict__ partial) {
  __shared__ float wps[256][9];
  __shared__ float red[256][8];
  int t = threadIdx.x;
  {
    float4 a = *(const float4*)(Wp + t*8);
    float4 b = *(const float4*)(Wp + t*8 + 4);
    wps[t][0]=a.x; wps[t][1]=a.y; wps[t][2]=a.z; wps[t][3]=a.w;
    wps[t][4]=b.x; wps[t][5]=b.y; wps[t][6]=b.z; wps[t][7]=b.w;
  }
  __syncthreads();
  int row = blockIdx.x*256 + t;
  const float* zr = z + (size_t)row*ND;
  float acc[8] = {};
  for (int d0 = 0; d0 < ND; d0 += 4) {
    float4 v = *(const float4*)(zr + d0);
    #pragma unroll
    for (int m = 0; m < 8; m++) {
      acc[m] += v.x*wps[d0][m] + v.y*wps[d0+1][m] + v.z*wps[d0+2][m] + v.w*wps[d0+3][m];
    }
  }
  float mx = -1e30f;
  #pragma unroll
  for (int m = 0; m < 8; m++) { acc[m] += bp[m]; mx = fmaxf(mx, acc[m]); }
  float s = 0.f;
  #pragma unroll
  for (int m = 0; m < 8; m++) { acc[m] = expf(acc[m]-mx); s += acc[m]; }
  float inv = 1.f/s;
  #pragma unroll
  for (int m = 0; m < 8; m++) red[t][m] = acc[m]*inv;
  __syncthreads();
  for (int q = 128; q > 0; q >>= 1) {
    if (t < q) { for (int m = 0; m < 8; m++) red[t][m] += red[t+q][m]; }
    __syncthreads();
  }
  if (t < 8) partial[blockIdx.x*8 + t] = red[0][t];
}

// ---------------- final scalar ----------------
__global__ void k_final(const float* __restrict__ greg, const float* __restrict__ partial,
                        float* __restrict__ out) {
  if (threadIdx.x == 0) {
    float us[8] = {};
    for (int b = 0; b < 16; b++)
      for (int m = 0; m < 8; m++) us[m] += partial[b*8 + m];
    float kl = 0.f;
    for (int m = 0; m < 8; m++) {
      float u = us[m] / (float)BN;
      kl += u*logf(fmaxf(u, 1e-8f)*(float)NM);
    }
    out[33554432] = greg[0] + 0.01f*kl;
  }
}

extern "C" void kernel_launch(void* const* d_in, const int* in_sizes, int n_in,
                              void* d_out, int out_size, void* d_ws, size_t ws_size,
                              hipStream_t stream) {
  const float* xd = (const float*)d_in[0];
  const float* xn = (const float*)d_in[1];
  const float* W1 = (const float*)d_in[2];
  const float* b1 = (const float*)d_in[3];
  const float* W2 = (const float*)d_in[4];
  const float* b2 = (const float*)d_in[5];
  const float* Wp = (const float*)d_in[6];
  const float* bp = (const float*)d_in[7];
  const float* Up = (const float*)d_in[8];
  float* out = (float*)d_out;
  float* ws  = (float*)d_ws;

  float* z   = ws + 0;                                     // 1,048,576 f
  float* hid = ws + 1048576;                               // dead after mlp2
  float* zh  = ws + 2097152;                               // dead after affinity
  unsigned short* DPb  = (unsigned short*)(ws + 3145728);  // 16.78M u16 (33.5 MB)
  unsigned short* PiGs = (unsigned short*)(ws + 11534336); // 4.19M u16
  unsigned short* Pis  = (unsigned short*)(ws + 13631488); // 4.19M u16
  float* gw    = ws + 15728640;
  float* alpha = ws + 15729152;
  float* G     = ws + 15729664;
  float* DG    = ws + 15731712;
  float* greg  = ws + 15733760;
  float* partial = ws + 15733761;
  // Est overlays dead hid+zh (exactly 2,097,152 floats = 4.19M u16)
  unsigned short* Est = (unsigned short*)(ws + 1048576);

  float* P = out;    // bias_log region doubles as P scratch (dead before qgemm writes)

  k_mlp1<<<dim3(4, 64), 256, 0, stream>>>(xd, xn, W1, b1, hid);
  k_mlp2<<<dim3(4, 64), 256, 0, stream>>>(hid, W2, b2, z);
  k_usage<<<16, 256, 0, stream>>>(z, Wp, bp, partial);
  k_zhnorm<<<4096, 256, 0, stream>>>(z, zh);
  k_affinity<<<1024, 256, 0, stream>>>(zh, P);
  k_dp<<<1024, 256, 0, stream>>>(P, DPb);
  k_slots<<<1, 256, 0, stream>>>(Up, G, DG, greg);
  k_gw<<<512, 512, 0, stream>>>(DPb, G, DG, PiGs, Pis, gw);
  k_alpha<<<1, 512, 0, stream>>>(gw, alpha);
  k_estack2<<<1024, 256, 0, stream>>>(PiGs, alpha, Est);
  k_qgemm<<<1024, 256, 0, stream>>>(Est, Pis, out);
  k_final<<<1, 64, 0, stream>>>(greg, partial, out);
}